// Round 3
// baseline (6859.032 us; speedup 1.0000x reference)
//
#include <hip/hip_runtime.h>
#include <hip/hip_bf16.h>

typedef __hip_bfloat16 bf16;

#define N_LIG 4096
#define N_REC 8192
#define E_LIG 65536
#define E_REC 262144
#define F_LIGc 15
#define F_RECc 27

__device__ __forceinline__ float ldf(const float* p, size_t i) { return p[i]; }
__device__ __forceinline__ float ldf(const bf16* p, size_t i) { return __bfloat162float(p[i]); }
__device__ __forceinline__ void stf(float* p, size_t i, float v) { p[i] = v; }
__device__ __forceinline__ void stf(bf16* p, size_t i, float v) { p[i] = __float2bfloat16(v); }

__constant__ float c_inv_sigma[15] = {
    1.0f, 0.6666666667f, 0.4444444444f, 0.2962962963f, 0.1975308642f,
    0.1316872428f, 0.08779149520f, 0.05852766346f, 0.03901844231f,
    0.02601229487f, 0.01734152992f, 0.01156101994f, 0.007707346628f,
    0.005138231085f, 0.003425487390f};

__device__ __forceinline__ float wave_sum(float v) {
    #pragma unroll
    for (int o = 32; o > 0; o >>= 1) v += __shfl_xor(v, o, 64);
    return v;
}

// ---------------- dtype detection: 0 = float32, 1 = bf16 ----------------
// mask holds exact 0.0/1.0. As f32 words: only 0x00000000 / 0x3F800000 appear.
// If the buffer is bf16, word-interpretation hits other patterns w.p. 0.5/word.
__global__ void detect_kernel(const unsigned* __restrict__ m, int* __restrict__ flag) {
    __shared__ int bad;
    if (threadIdx.x == 0) bad = 0;
    __syncthreads();
    for (int i = threadIdx.x; i < 4096; i += 256) {
        unsigned w = m[i];
        if (w != 0u && w != 0x3F800000u) bad = 1;
    }
    __syncthreads();
    if (threadIdx.x == 0) *flag = bad;
}

// ---------------- zero scratch ----------------
__global__ void zero_kernel(float* __restrict__ p, int n) {
    int i = blockIdx.x * blockDim.x + threadIdx.x;
    if (i < n) p[i] = 0.f;
}

// ---------------- fused edge kernel (1 wave per edge) ----------------
template <typename FT, int F>
__global__ __launch_bounds__(64) void edge_kernel(
    const int* __restrict__ dflag, int want,
    const FT* __restrict__ coords, const FT* __restrict__ h,
    const int* __restrict__ src, const int* __restrict__ dst,
    const FT* __restrict__ efeat,
    const FT* __restrict__ w1, const FT* __restrict__ b1,
    const FT* __restrict__ g, const FT* __restrict__ bt,
    const FT* __restrict__ w2, const FT* __restrict__ b2,
    const FT* __restrict__ cw1, const FT* __restrict__ cb1,
    const FT* __restrict__ cw2, const FT* __restrict__ cb2,
    float* __restrict__ aggr, float* __restrict__ cnt, float* __restrict__ xacc)
{
    if (*dflag != want) return;
    constexpr int IN = 128 + F + 15;
    int e = blockIdx.x;
    int j = threadIdx.x;
    __shared__ float xin[IN];
    __shared__ float xr_s[3];
    __shared__ float hbuf[64];
    __shared__ float msg_s[64];

    int s = src[e], d = dst[e];
    xin[j]      = ldf(h, (size_t)s * 64 + j);
    xin[64 + j] = ldf(h, (size_t)d * 64 + j);
    if (j < F) xin[128 + j] = ldf(efeat, (size_t)e * F + j);
    if (j < 3) xr_s[j] = ldf(coords, s * 3 + j) - ldf(coords, d * 3 + j);
    __syncthreads();
    float d2 = xr_s[0] * xr_s[0] + xr_s[1] * xr_s[1] + xr_s[2] * xr_s[2];
    if (j < 15) xin[128 + F + j] = __expf(-d2 * c_inv_sigma[j]);
    __syncthreads();

    float acc = ldf(b1, j);
    #pragma unroll 4
    for (int i = 0; i < IN; ++i) acc += xin[i] * ldf(w1, i * 64 + j);
    acc = acc > 0.f ? acc : 0.01f * acc;
    float mean = wave_sum(acc) * (1.f / 64.f);
    float cv = acc - mean;
    float var = wave_sum(cv * cv) * (1.f / 64.f);
    float y = cv * rsqrtf(var + 1e-5f) * ldf(g, j) + ldf(bt, j);
    hbuf[j] = y;
    __syncthreads();

    float msg = ldf(b2, j);
    #pragma unroll 8
    for (int i = 0; i < 64; ++i) msg += hbuf[i] * ldf(w2, i * 64 + j);
    msg_s[j] = msg;
    __syncthreads();

    float t = ldf(cb1, j);
    #pragma unroll 8
    for (int i = 0; i < 64; ++i) t += msg_s[i] * ldf(cw1, i * 64 + j);
    t = t > 0.f ? t : 0.01f * t;
    float coef = wave_sum(t * ldf(cw2, j)) + ldf(cb2, 0);

    atomicAdd(&aggr[(size_t)d * 64 + j], msg);
    if (j == 0) atomicAdd(&cnt[d], 1.0f);
    if (j < 3) atomicAdd(&xacc[d * 3 + j], xr_s[j] * coef);
}

// ---------------- k/v projection: out = (lrelu?)(h @ w) ----------------
template <typename FT, typename OT>
__global__ __launch_bounds__(64) void linear64_kernel(
    const int* __restrict__ dflag, int want,
    const FT* __restrict__ h, const FT* __restrict__ w,
    OT* __restrict__ out, int do_lrelu)
{
    if (*dflag != want) return;
    int node = blockIdx.x;
    int j = threadIdx.x;
    __shared__ float x[64];
    x[j] = ldf(h, (size_t)node * 64 + j);
    __syncthreads();
    float acc = 0.f;
    #pragma unroll 8
    for (int i = 0; i < 64; ++i) acc += x[i] * ldf(w, i * 64 + j);
    if (do_lrelu) acc = acc > 0.f ? acc : 0.01f * acc;
    stf(out, (size_t)node * 64 + j, acc);
}

// ---------------- mask transpose, out[c][r] = in[r][c] ----------------
template <typename FT>
__global__ __launch_bounds__(256) void transpose_kernel(
    const int* __restrict__ dflag, int want,
    const FT* __restrict__ in, FT* __restrict__ out, int in_rows, int in_cols)
{
    if (*dflag != want) return;
    __shared__ FT tile[32][33];
    int c0 = blockIdx.x * 32, r0 = blockIdx.y * 32;
    int tx = threadIdx.x, ty = threadIdx.y;  // 32 x 8
    for (int i = ty; i < 32; i += 8) tile[i][tx] = in[(size_t)(r0 + i) * in_cols + c0 + tx];
    __syncthreads();
    for (int i = ty; i < 32; i += 8) out[(size_t)(c0 + i) * in_rows + r0 + tx] = tile[tx][i];
}

// ---------------- masked softmax-attention, one block per row ----------------
template <typename FT, typename KT>
__global__ __launch_bounds__(256) void attn_kernel(
    const int* __restrict__ dflag, int want,
    const FT* __restrict__ h, const FT* __restrict__ qw,
    const KT* __restrict__ k, const KT* __restrict__ v,
    const FT* __restrict__ mask, long mrs, long mcs,
    FT* __restrict__ out, int n_cols)
{
    if (*dflag != want) return;
    int row = blockIdx.x;
    int tid = threadIdx.x;
    extern __shared__ float sc[];
    __shared__ float hrow[64];
    __shared__ float qrow[64];
    __shared__ float red[4];
    __shared__ float opart[4][64];

    if (tid < 64) hrow[tid] = ldf(h, (size_t)row * 64 + tid);
    __syncthreads();
    if (tid < 64) {
        float a = 0.f;
        #pragma unroll 8
        for (int i = 0; i < 64; ++i) a += hrow[i] * ldf(qw, i * 64 + tid);
        qrow[tid] = a > 0.f ? a : 0.01f * a;
    }
    __syncthreads();

    float lmax = -1e30f;
    for (int c = tid; c < n_cols; c += 256) {
        const KT* kr = k + (size_t)c * 64;
        float s = 0.f;
        #pragma unroll 8
        for (int i = 0; i < 64; ++i) s += qrow[i] * ldf(kr, i);
        float m = ldf(mask, (size_t)row * mrs + (size_t)c * mcs);
        s = m * s - 1000.f * (1.f - m);
        sc[c] = s;
        lmax = fmaxf(lmax, s);
    }
    #pragma unroll
    for (int o = 32; o > 0; o >>= 1) lmax = fmaxf(lmax, __shfl_xor(lmax, o, 64));
    int wid = tid >> 6;
    if ((tid & 63) == 0) red[wid] = lmax;
    __syncthreads();
    float bmax = fmaxf(fmaxf(red[0], red[1]), fmaxf(red[2], red[3]));
    __syncthreads();

    float lsum = 0.f;
    for (int c = tid; c < n_cols; c += 256) {
        float e = __expf(sc[c] - bmax);
        sc[c] = e;
        lsum += e;
    }
    lsum = wave_sum(lsum);
    if ((tid & 63) == 0) red[wid] = lsum;
    __syncthreads();
    float inv = 1.f / (red[0] + red[1] + red[2] + red[3]);

    int dd = tid & 63;
    float o = 0.f;
    for (int c = wid; c < n_cols; c += 4) {
        o += sc[c] * ldf(v, (size_t)c * 64 + dd);
    }
    opart[wid][dd] = o;
    __syncthreads();
    if (wid == 0)
        stf(out, (size_t)row * 64 + dd,
            (opart[0][dd] + opart[1][dd] + opart[2][dd] + opart[3][dd]) * inv);
}

// ---------------- node feature update (att parked in out region; aliases h_out) ----
template <typename FT>
__global__ __launch_bounds__(64) void node_kernel(
    const int* __restrict__ dflag, int want,
    const FT* __restrict__ h, const float* __restrict__ aggr,
    const float* __restrict__ cnt, const FT* att,  // NOT restrict: aliases h_out
    const FT* __restrict__ orig_h,
    const FT* __restrict__ w1, const FT* __restrict__ b1,
    const FT* __restrict__ g, const FT* __restrict__ bt,
    const FT* __restrict__ w2, const FT* __restrict__ b2,
    FT* h_out)  // NOT restrict
{
    if (*dflag != want) return;
    int node = blockIdx.x;
    int j = threadIdx.x;
    __shared__ float xin[256];
    __shared__ float hbuf[64];
    float invc = 1.f / fmaxf(cnt[node], 1.f);
    float hv = ldf(h, (size_t)node * 64 + j);
    xin[j]       = hv;
    xin[64 + j]  = aggr[(size_t)node * 64 + j] * invc;
    xin[128 + j] = ldf(att, (size_t)node * 64 + j);
    xin[192 + j] = ldf(orig_h, (size_t)node * 64 + j);
    __syncthreads();
    float acc = ldf(b1, j);
    #pragma unroll 4
    for (int i = 0; i < 256; ++i) acc += xin[i] * ldf(w1, i * 64 + j);
    acc = acc > 0.f ? acc : 0.01f * acc;
    float mean = wave_sum(acc) * (1.f / 64.f);
    float cv = acc - mean;
    float var = wave_sum(cv * cv) * (1.f / 64.f);
    float y = cv * rsqrtf(var + 1e-5f) * ldf(g, j) + ldf(bt, j);
    hbuf[j] = y;
    __syncthreads();
    float o = ldf(b2, j);
    #pragma unroll 8
    for (int i = 0; i < 64; ++i) o += hbuf[i] * ldf(w2, i * 64 + j);
    stf(h_out, (size_t)node * 64 + j, 0.5f * o + 0.5f * hv);
}

// ---------------- coordinate output ----------------
template <typename FT>
__global__ void coord_kernel(
    const int* __restrict__ dflag, int want,
    const FT* __restrict__ orig, const FT* __restrict__ coords,
    const float* __restrict__ xacc, const float* __restrict__ cnt,
    FT* __restrict__ out, int n3)
{
    if (*dflag != want) return;
    int i = blockIdx.x * blockDim.x + threadIdx.x;
    if (i >= n3) return;
    int node = i / 3;
    float invc = 1.f / fmaxf(cnt[node], 1.f);
    stf(out, i, 0.25f * ldf(orig, i) + 0.75f * ldf(coords, i) + xacc[i] * invc);
}

// ================= pipeline per dtype (templated host helper) =================
template <typename FT, typename KT>
static void run_pipeline(void* const* d_in, void* d_out, int want,
                         int* dflag, float* aggr_l, float* aggr_r,
                         float* cnt_l, float* cnt_r, float* xacc_l, float* xacc_r,
                         KT* kv_base, FT* maskT, bool use_T, hipStream_t stream)
{
    const FT* coords_lig      = (const FT*)d_in[0];
    const FT* h_lig           = (const FT*)d_in[1];
    const FT* orig_h_lig      = (const FT*)d_in[2];
    const FT* orig_coords_lig = (const FT*)d_in[3];
    const FT* coords_rec      = (const FT*)d_in[4];
    const FT* h_rec           = (const FT*)d_in[5];
    const FT* orig_h_rec      = (const FT*)d_in[6];
    const FT* orig_coords_rec = (const FT*)d_in[7];
    const int* lig_src   = (const int*)d_in[8];
    const int* lig_dst   = (const int*)d_in[9];
    const FT*  lig_efeat = (const FT*)d_in[10];
    const int* rec_src   = (const int*)d_in[11];
    const int* rec_dst   = (const int*)d_in[12];
    const FT*  rec_efeat = (const FT*)d_in[13];
    const FT*  mask      = (const FT*)d_in[14];
    const FT *lig_em_w1 = (const FT*)d_in[15], *lig_em_b1 = (const FT*)d_in[16];
    const FT *lig_em_g  = (const FT*)d_in[17], *lig_em_bt = (const FT*)d_in[18];
    const FT *lig_em_w2 = (const FT*)d_in[19], *lig_em_b2 = (const FT*)d_in[20];
    const FT *rec_em_w1 = (const FT*)d_in[21], *rec_em_b1 = (const FT*)d_in[22];
    const FT *rec_em_g  = (const FT*)d_in[23], *rec_em_bt = (const FT*)d_in[24];
    const FT *rec_em_w2 = (const FT*)d_in[25], *rec_em_b2 = (const FT*)d_in[26];
    const FT *lig_cm_w1 = (const FT*)d_in[27], *lig_cm_b1 = (const FT*)d_in[28];
    const FT *lig_cm_w2 = (const FT*)d_in[29], *lig_cm_b2 = (const FT*)d_in[30];
    const FT *rec_cm_w1 = (const FT*)d_in[31], *rec_cm_b1 = (const FT*)d_in[32];
    const FT *rec_cm_w2 = (const FT*)d_in[33], *rec_cm_b2 = (const FT*)d_in[34];
    const FT *q_lig_w = (const FT*)d_in[35], *k_lig_w = (const FT*)d_in[36];
    const FT *v_lig_w = (const FT*)d_in[37], *q_rec_w = (const FT*)d_in[38];
    const FT *k_rec_w = (const FT*)d_in[39], *v_rec_w = (const FT*)d_in[40];
    const FT *lig_nm_w1 = (const FT*)d_in[41], *lig_nm_b1 = (const FT*)d_in[42];
    const FT *lig_nm_g  = (const FT*)d_in[43], *lig_nm_bt = (const FT*)d_in[44];
    const FT *lig_nm_w2 = (const FT*)d_in[45], *lig_nm_b2 = (const FT*)d_in[46];
    const FT *rec_nm_w1 = (const FT*)d_in[47], *rec_nm_b1 = (const FT*)d_in[48];
    const FT *rec_nm_g  = (const FT*)d_in[49], *rec_nm_bt = (const FT*)d_in[50];
    const FT *rec_nm_w2 = (const FT*)d_in[51], *rec_nm_b2 = (const FT*)d_in[52];

    KT* k_l = kv_base;
    KT* v_l = k_l + (size_t)N_LIG * 64;
    KT* k_r = v_l + (size_t)N_LIG * 64;
    KT* v_r = k_r + (size_t)N_REC * 64;

    FT* out = (FT*)d_out;
    FT* x_lig_o = out;                 // 4096*3
    FT* h_lig_o = out + 12288;         // 4096*64 (att_l parking)
    FT* x_rec_o = out + 274432;        // 8192*3
    FT* h_rec_o = out + 299008;        // 8192*64 (att_r parking)

    if (use_T) {
        dim3 tb(32, 8);
        dim3 tg(N_REC / 32, N_LIG / 32);
        transpose_kernel<FT><<<tg, tb, 0, stream>>>(dflag, want, mask, maskT, N_LIG, N_REC);
    }

    linear64_kernel<FT, KT><<<N_LIG, 64, 0, stream>>>(dflag, want, h_lig, k_lig_w, k_l, 1);
    linear64_kernel<FT, KT><<<N_LIG, 64, 0, stream>>>(dflag, want, h_lig, v_lig_w, v_l, 0);
    linear64_kernel<FT, KT><<<N_REC, 64, 0, stream>>>(dflag, want, h_rec, k_rec_w, k_r, 1);
    linear64_kernel<FT, KT><<<N_REC, 64, 0, stream>>>(dflag, want, h_rec, v_rec_w, v_r, 0);

    edge_kernel<FT, F_LIGc><<<E_LIG, 64, 0, stream>>>(dflag, want,
        coords_lig, h_lig, lig_src, lig_dst, lig_efeat,
        lig_em_w1, lig_em_b1, lig_em_g, lig_em_bt, lig_em_w2, lig_em_b2,
        lig_cm_w1, lig_cm_b1, lig_cm_w2, lig_cm_b2,
        aggr_l, cnt_l, xacc_l);
    edge_kernel<FT, F_RECc><<<E_REC, 64, 0, stream>>>(dflag, want,
        coords_rec, h_rec, rec_src, rec_dst, rec_efeat,
        rec_em_w1, rec_em_b1, rec_em_g, rec_em_bt, rec_em_w2, rec_em_b2,
        rec_cm_w1, rec_cm_b1, rec_cm_w2, rec_cm_b2,
        aggr_r, cnt_r, xacc_r);

    attn_kernel<FT, KT><<<N_LIG, 256, N_REC * sizeof(float), stream>>>(dflag, want,
        h_lig, q_lig_w, k_r, v_r, mask, (long)N_REC, 1L, h_lig_o, N_REC);
    if (use_T)
        attn_kernel<FT, KT><<<N_REC, 256, N_LIG * sizeof(float), stream>>>(dflag, want,
            h_rec, q_rec_w, k_l, v_l, maskT, (long)N_LIG, 1L, h_rec_o, N_LIG);
    else
        attn_kernel<FT, KT><<<N_REC, 256, N_LIG * sizeof(float), stream>>>(dflag, want,
            h_rec, q_rec_w, k_l, v_l, mask, 1L, (long)N_REC, h_rec_o, N_LIG);

    node_kernel<FT><<<N_LIG, 64, 0, stream>>>(dflag, want,
        h_lig, aggr_l, cnt_l, h_lig_o, orig_h_lig,
        lig_nm_w1, lig_nm_b1, lig_nm_g, lig_nm_bt, lig_nm_w2, lig_nm_b2, h_lig_o);
    node_kernel<FT><<<N_REC, 64, 0, stream>>>(dflag, want,
        h_rec, aggr_r, cnt_r, h_rec_o, orig_h_rec,
        rec_nm_w1, rec_nm_b1, rec_nm_g, rec_nm_bt, rec_nm_w2, rec_nm_b2, h_rec_o);

    coord_kernel<FT><<<(N_LIG * 3 + 255) / 256, 256, 0, stream>>>(dflag, want,
        orig_coords_lig, coords_lig, xacc_l, cnt_l, x_lig_o, N_LIG * 3);
    coord_kernel<FT><<<(N_REC * 3 + 255) / 256, 256, 0, stream>>>(dflag, want,
        orig_coords_rec, coords_rec, xacc_r, cnt_r, x_rec_o, N_REC * 3);
}

extern "C" void kernel_launch(void* const* d_in, const int* in_sizes, int n_in,
                              void* d_out, int out_size, void* d_ws, size_t ws_size,
                              hipStream_t stream)
{
    char* wsb = (char*)d_ws;
    int* dflag = (int*)wsb;                          // 16 B slot
    float* aggr_l = (float*)(wsb + 16);
    float* aggr_r = aggr_l + (size_t)N_LIG * 64;
    float* cnt_l  = aggr_r + (size_t)N_REC * 64;
    float* cnt_r  = cnt_l + N_LIG;
    float* xacc_l = cnt_r + N_REC;
    float* xacc_r = xacc_l + (size_t)N_LIG * 3;
    const size_t zero_floats =
        (size_t)N_LIG * 64 + (size_t)N_REC * 64 + N_LIG + N_REC + N_LIG * 3 + N_REC * 3;
    const size_t core_b = 16 + zero_floats * 4;
    const size_t kv_elems = (size_t)(N_LIG + N_REC) * 64 * 2;
    const bool kv_f32 = ws_size >= core_b + kv_elems * 4;
    const size_t kv_b = kv_elems * (kv_f32 ? 4 : 2);
    void* kv_base = (void*)(wsb + core_b);
    void* maskT = (void*)(wsb + core_b + kv_b);
    const bool t_bf16 = ws_size >= core_b + kv_b + (size_t)N_LIG * N_REC * 2;
    const bool t_f32  = ws_size >= core_b + kv_b + (size_t)N_LIG * N_REC * 4;

    detect_kernel<<<1, 256, 0, stream>>>((const unsigned*)d_in[14], dflag);
    zero_kernel<<<((int)zero_floats + 255) / 256, 256, 0, stream>>>(aggr_l, (int)zero_floats);

    if (kv_f32) {
        run_pipeline<float, float>(d_in, d_out, 0, dflag, aggr_l, aggr_r,
                                   cnt_l, cnt_r, xacc_l, xacc_r,
                                   (float*)kv_base, (float*)maskT, t_f32, stream);
        run_pipeline<bf16, float>(d_in, d_out, 1, dflag, aggr_l, aggr_r,
                                  cnt_l, cnt_r, xacc_l, xacc_r,
                                  (float*)kv_base, (bf16*)maskT, t_bf16, stream);
    } else {
        run_pipeline<float, bf16>(d_in, d_out, 0, dflag, aggr_l, aggr_r,
                                  cnt_l, cnt_r, xacc_l, xacc_r,
                                  (bf16*)kv_base, (float*)maskT, t_f32, stream);
        run_pipeline<bf16, bf16>(d_in, d_out, 1, dflag, aggr_l, aggr_r,
                                 cnt_l, cnt_r, xacc_l, xacc_r,
                                 (bf16*)kv_base, (bf16*)maskT, t_bf16, stream);
    }
}

// Round 5
// 2281.359 us; speedup vs baseline: 3.0066x; 3.0066x over previous
//
#include <hip/hip_runtime.h>
#include <hip/hip_bf16.h>

typedef __hip_bfloat16 bf16;

#define N_LIG 4096
#define N_REC 8192
#define E_LIG 65536
#define E_REC 262144
#define F_LIGc 15
#define F_RECc 27

__device__ __forceinline__ float ldf(const float* p, size_t i) { return p[i]; }
__device__ __forceinline__ float ldf(const bf16* p, size_t i) { return __bfloat162float(p[i]); }
__device__ __forceinline__ void stf(float* p, size_t i, float v) { p[i] = v; }
__device__ __forceinline__ void stf(bf16* p, size_t i, float v) { p[i] = __float2bfloat16(v); }
__device__ __forceinline__ float4 ld4(const float* p, size_t i) { return *(const float4*)(p + i); }
__device__ __forceinline__ float4 ld4(const bf16* p, size_t i) {
    float4 r; r.x = ldf(p, i); r.y = ldf(p, i + 1); r.z = ldf(p, i + 2); r.w = ldf(p, i + 3);
    return r;
}

__constant__ float c_inv_sigma[15] = {
    1.0f, 0.6666666667f, 0.4444444444f, 0.2962962963f, 0.1975308642f,
    0.1316872428f, 0.08779149520f, 0.05852766346f, 0.03901844231f,
    0.02601229487f, 0.01734152992f, 0.01156101994f, 0.007707346628f,
    0.005138231085f, 0.003425487390f};

__device__ __forceinline__ float wave_sum(float v) {
    #pragma unroll
    for (int o = 32; o > 0; o >>= 1) v += __shfl_xor(v, o, 64);
    return v;
}

// ---------------- dtype detection: 0 = float32, 1 = bf16 ----------------
__global__ void detect_kernel(const unsigned* __restrict__ m, int* __restrict__ flag) {
    __shared__ int bad;
    if (threadIdx.x == 0) bad = 0;
    __syncthreads();
    for (int i = threadIdx.x; i < 4096; i += 256) {
        unsigned w = m[i];
        if (w != 0u && w != 0x3F800000u) bad = 1;
    }
    __syncthreads();
    if (threadIdx.x == 0) *flag = bad;
}

__global__ void zero_kernel(float* __restrict__ p, int n) {
    int i = blockIdx.x * blockDim.x + threadIdx.x;
    if (i < n) p[i] = 0.f;
}

// ---------------- fused edge kernel (1 wave per edge) ----------------
template <typename FT, int F>
__global__ __launch_bounds__(64) void edge_kernel(
    const int* __restrict__ dflag, int want,
    const FT* __restrict__ coords, const FT* __restrict__ h,
    const int* __restrict__ src, const int* __restrict__ dst,
    const FT* __restrict__ efeat,
    const FT* __restrict__ w1, const FT* __restrict__ b1,
    const FT* __restrict__ g, const FT* __restrict__ bt,
    const FT* __restrict__ w2, const FT* __restrict__ b2,
    const FT* __restrict__ cw1, const FT* __restrict__ cb1,
    const FT* __restrict__ cw2, const FT* __restrict__ cb2,
    float* __restrict__ aggr, float* __restrict__ cnt, float* __restrict__ xacc)
{
    if (*dflag != want) return;
    constexpr int IN = 128 + F + 15;
    int e = blockIdx.x;
    int j = threadIdx.x;
    __shared__ float xin[IN];
    __shared__ float xr_s[3];
    __shared__ float hbuf[64];
    __shared__ float msg_s[64];

    int s = src[e], d = dst[e];
    xin[j]      = ldf(h, (size_t)s * 64 + j);
    xin[64 + j] = ldf(h, (size_t)d * 64 + j);
    if (j < F) xin[128 + j] = ldf(efeat, (size_t)e * F + j);
    if (j < 3) xr_s[j] = ldf(coords, s * 3 + j) - ldf(coords, d * 3 + j);
    __syncthreads();
    float d2 = xr_s[0] * xr_s[0] + xr_s[1] * xr_s[1] + xr_s[2] * xr_s[2];
    if (j < 15) xin[128 + F + j] = __expf(-d2 * c_inv_sigma[j]);
    __syncthreads();

    float acc = ldf(b1, j);
    #pragma unroll 4
    for (int i = 0; i < IN; ++i) acc += xin[i] * ldf(w1, i * 64 + j);
    acc = acc > 0.f ? acc : 0.01f * acc;
    float mean = wave_sum(acc) * (1.f / 64.f);
    float cv = acc - mean;
    float var = wave_sum(cv * cv) * (1.f / 64.f);
    float y = cv * rsqrtf(var + 1e-5f) * ldf(g, j) + ldf(bt, j);
    hbuf[j] = y;
    __syncthreads();

    float msg = ldf(b2, j);
    #pragma unroll 8
    for (int i = 0; i < 64; ++i) msg += hbuf[i] * ldf(w2, i * 64 + j);
    msg_s[j] = msg;
    __syncthreads();

    float t = ldf(cb1, j);
    #pragma unroll 8
    for (int i = 0; i < 64; ++i) t += msg_s[i] * ldf(cw1, i * 64 + j);
    t = t > 0.f ? t : 0.01f * t;
    float coef = wave_sum(t * ldf(cw2, j)) + ldf(cb2, 0);

    atomicAdd(&aggr[(size_t)d * 64 + j], msg);
    if (j == 0) atomicAdd(&cnt[d], 1.0f);
    if (j < 3) atomicAdd(&xacc[d * 3 + j], xr_s[j] * coef);
}

// ---------------- k/v projection ----------------
template <typename FT, typename OT>
__global__ __launch_bounds__(64) void linear64_kernel(
    const int* __restrict__ dflag, int want,
    const FT* __restrict__ h, const FT* __restrict__ w,
    OT* __restrict__ out, int do_lrelu)
{
    if (*dflag != want) return;
    int node = blockIdx.x;
    int j = threadIdx.x;
    __shared__ float x[64];
    x[j] = ldf(h, (size_t)node * 64 + j);
    __syncthreads();
    float acc = 0.f;
    #pragma unroll 8
    for (int i = 0; i < 64; ++i) acc += x[i] * ldf(w, i * 64 + j);
    if (do_lrelu) acc = acc > 0.f ? acc : 0.01f * acc;
    stf(out, (size_t)node * 64 + j, acc);
}

// ---------------- u8 mask build: m8[r][c], m8T[c][r] ----------------
template <typename FT>
__global__ __launch_bounds__(256) void build_masks(
    const int* __restrict__ dflag, int want,
    const FT* __restrict__ mask, unsigned char* __restrict__ m8,
    unsigned char* __restrict__ m8T, int R, int C)
{
    if (*dflag != want) return;
    __shared__ __align__(16) unsigned char tl[64 * 80];
    int r0 = blockIdx.y * 64, c0 = blockIdx.x * 64;
    int t = threadIdx.x;
    int cs = (t & 15) * 4;
    #pragma unroll
    for (int rr = 0; rr < 4; ++rr) {
        int r = (t >> 4) + rr * 16;   // full 0..63 coverage
        unsigned b0 = (ldf(mask, (size_t)(r0 + r) * C + c0 + cs + 0) != 0.f);
        unsigned b1 = (ldf(mask, (size_t)(r0 + r) * C + c0 + cs + 1) != 0.f);
        unsigned b2 = (ldf(mask, (size_t)(r0 + r) * C + c0 + cs + 2) != 0.f);
        unsigned b3 = (ldf(mask, (size_t)(r0 + r) * C + c0 + cs + 3) != 0.f);
        *(unsigned*)&m8[(size_t)(r0 + r) * C + c0 + cs] = b0 | (b1 << 8) | (b2 << 16) | (b3 << 24);
        tl[(cs + 0) * 80 + r] = (unsigned char)b0;
        tl[(cs + 1) * 80 + r] = (unsigned char)b1;
        tl[(cs + 2) * 80 + r] = (unsigned char)b2;
        tl[(cs + 3) * 80 + r] = (unsigned char)b3;
    }
    __syncthreads();
    {
        int c = t >> 2, rs = (t & 3) * 16;
        *(uint4*)&m8T[(size_t)(c0 + c) * R + r0 + rs] = *(const uint4*)&tl[c * 80 + rs];
    }
}

// ---------------- tiled masked flash attention with column splits ----------------
// 64 rows x 64-col tiles; K and V share one LDS buffer (V staged after S).
// LDS total ~58.4 KB < 64 KB/WG limit.
template <typename FT, typename KT, int MMODE>  // MMODE 0: u8 mask, 1: strided FT mask
__global__ __launch_bounds__(256) void attn_tiled(
    const int* __restrict__ dflag, int want,
    const FT* __restrict__ h, const FT* __restrict__ qw,
    const KT* __restrict__ kk, const KT* __restrict__ vv,
    const unsigned char* __restrict__ m8,
    const FT* __restrict__ maskf, long mrs, long mcs,
    float* __restrict__ pO, float* __restrict__ pM, float* __restrict__ pL,
    int n_rows, int n_cols, int nsplit)
{
    if (*dflag != want) return;
    const int t = threadIdx.x;
    const int rb = blockIdx.x / nsplit;
    const int sp = blockIdx.x - rb * nsplit;
    const int r0 = rb * 64;
    const int cols_per = n_cols / nsplit;
    const int c_begin = sp * cols_per;

    __shared__ __align__(16) float q_s[64 * 68];
    __shared__ __align__(16) float ktv[64 * 68];   // K tile, then V tile (transposed)
    __shared__ __align__(16) float p_s[64 * 68];
    __shared__ float mrow[64], lrow[64], anew[64], mnew[64];
    __shared__ float lpart[256];
    __shared__ __align__(16) unsigned char mt[4096];

    const int cg = t & 31;        // col/dim group: owns cg and cg+32
    const int rg = (t >> 5) * 8;  // row group: 8 rows

    // ---- Q tile = lrelu(h[r0:r0+64] @ qw); h staged in p_s, qw^T in ktv ----
    for (int u = 0; u < 16; ++u) {
        int i = t + 256 * u;
        int r = i >> 6, d = i & 63;
        p_s[r * 68 + d] = ldf(h, (size_t)(r0 + r) * 64 + d);
        ktv[d * 68 + r] = ldf(qw, (size_t)r * 64 + d);  // ktv[j][din] = qw[din*64+j]
    }
    __syncthreads();
    {
        float a0[8], a1[8];
        #pragma unroll
        for (int x = 0; x < 8; ++x) { a0[x] = 0.f; a1[x] = 0.f; }
        for (int d = 0; d < 64; d += 4) {
            float4 b0 = *(const float4*)&ktv[cg * 68 + d];
            float4 b1 = *(const float4*)&ktv[(cg + 32) * 68 + d];
            #pragma unroll
            for (int x = 0; x < 8; ++x) {
                float4 a = *(const float4*)&p_s[(rg + x) * 68 + d];
                a0[x] += a.x * b0.x + a.y * b0.y + a.z * b0.z + a.w * b0.w;
                a1[x] += a.x * b1.x + a.y * b1.y + a.z * b1.z + a.w * b1.w;
            }
        }
        __syncthreads();
        #pragma unroll
        for (int x = 0; x < 8; ++x) {
            float v0 = a0[x]; v0 = v0 > 0.f ? v0 : 0.01f * v0;
            float v1 = a1[x]; v1 = v1 > 0.f ? v1 : 0.01f * v1;
            q_s[(rg + x) * 68 + cg] = v0;
            q_s[(rg + x) * 68 + cg + 32] = v1;
        }
    }
    if (t < 64) { mrow[t] = -1e30f; lrow[t] = 0.f; }
    float o0[8], o1[8];
    #pragma unroll
    for (int x = 0; x < 8; ++x) { o0[x] = 0.f; o1[x] = 0.f; }
    __syncthreads();

    for (int c0 = c_begin; c0 < c_begin + cols_per; c0 += 64) {
        // ---- stage K tile + mask tile ----
        #pragma unroll
        for (int u = 0; u < 4; ++u) {
            int i4 = (t + 256 * u) * 4;
            int c = i4 >> 6, d = i4 & 63;
            float4 k4 = ld4(kk, (size_t)(c0 + c) * 64 + d);
            *(float4*)&ktv[c * 68 + d] = k4;
        }
        if (MMODE == 0) {
            int r = t >> 2, seg = (t & 3) * 16;
            *(uint4*)&mt[r * 64 + seg] =
                *(const uint4*)&m8[(size_t)(r0 + r) * n_cols + c0 + seg];
        } else {
            #pragma unroll
            for (int u = 0; u < 16; ++u) {
                int i = t + 256 * u;
                int r = i >> 6, c = i & 63;
                mt[r * 64 + c] = (unsigned char)(
                    ldf(maskf, (size_t)(r0 + r) * mrs + (size_t)(c0 + c) * mcs) != 0.f);
            }
        }
        __syncthreads();

        // ---- S = Q K^T, masked ----
        {
            float s0[8], s1[8];
            #pragma unroll
            for (int x = 0; x < 8; ++x) { s0[x] = 0.f; s1[x] = 0.f; }
            for (int d = 0; d < 64; d += 4) {
                float4 b0 = *(const float4*)&ktv[cg * 68 + d];
                float4 b1 = *(const float4*)&ktv[(cg + 32) * 68 + d];
                #pragma unroll
                for (int x = 0; x < 8; ++x) {
                    float4 a = *(const float4*)&q_s[(rg + x) * 68 + d];
                    s0[x] += a.x * b0.x + a.y * b0.y + a.z * b0.z + a.w * b0.w;
                    s1[x] += a.x * b1.x + a.y * b1.y + a.z * b1.z + a.w * b1.w;
                }
            }
            #pragma unroll
            for (int x = 0; x < 8; ++x) {
                int r = rg + x;
                p_s[r * 68 + cg]      = mt[r * 64 + cg]      ? s0[x] : -1000.f;
                p_s[r * 68 + cg + 32] = mt[r * 64 + cg + 32] ? s1[x] : -1000.f;
            }
        }
        __syncthreads();  // p_s ready; K in ktv now dead

        // ---- stage V (transposed) into ktv; concurrently rowmax on t<64 ----
        #pragma unroll
        for (int u = 0; u < 4; ++u) {
            int i4 = (t + 256 * u) * 4;
            int c = i4 >> 6, d = i4 & 63;
            float4 v4 = ld4(vv, (size_t)(c0 + c) * 64 + d);
            ktv[(d + 0) * 68 + c] = v4.x;
            ktv[(d + 1) * 68 + c] = v4.y;
            ktv[(d + 2) * 68 + c] = v4.z;
            ktv[(d + 3) * 68 + c] = v4.w;
        }
        if (t < 64) {
            float mx = -1e30f;
            for (int c = 0; c < 64; c += 4) {
                float4 s4 = *(const float4*)&p_s[t * 68 + c];
                mx = fmaxf(mx, fmaxf(fmaxf(s4.x, s4.y), fmaxf(s4.z, s4.w)));
            }
            float mn = fmaxf(mrow[t], mx);
            mnew[t] = mn;
            anew[t] = __expf(mrow[t] - mn);
            mrow[t] = mn;
        }
        __syncthreads();  // mnew/anew visible; V writes complete

        // ---- P = exp(S - m), partial row sums ----
        {
            int r = t >> 2, seg = (t & 3) * 16;
            float mr = mnew[r];
            float ps = 0.f;
            #pragma unroll
            for (int c = seg; c < seg + 16; c += 4) {
                float4 s4 = *(float4*)&p_s[r * 68 + c];
                s4.x = __expf(s4.x - mr);
                s4.y = __expf(s4.y - mr);
                s4.z = __expf(s4.z - mr);
                s4.w = __expf(s4.w - mr);
                ps += s4.x + s4.y + s4.z + s4.w;
                *(float4*)&p_s[r * 68 + c] = s4;
            }
            lpart[t] = ps;
        }
        __syncthreads();  // exp'd p_s + lpart ready
        if (t < 64)
            lrow[t] = lrow[t] * anew[t] +
                      lpart[t * 4] + lpart[t * 4 + 1] + lpart[t * 4 + 2] + lpart[t * 4 + 3];

        // ---- O = O*alpha + P @ V ----
        {
            #pragma unroll
            for (int x = 0; x < 8; ++x) {
                float a = anew[rg + x];
                o0[x] *= a;
                o1[x] *= a;
            }
            for (int c = 0; c < 64; c += 4) {
                float4 b0 = *(const float4*)&ktv[cg * 68 + c];
                float4 b1 = *(const float4*)&ktv[(cg + 32) * 68 + c];
                #pragma unroll
                for (int x = 0; x < 8; ++x) {
                    float4 p = *(const float4*)&p_s[(rg + x) * 68 + c];
                    o0[x] += p.x * b0.x + p.y * b0.y + p.z * b0.z + p.w * b0.w;
                    o1[x] += p.x * b1.x + p.y * b1.y + p.z * b1.z + p.w * b1.w;
                }
            }
        }
        __syncthreads();  // PV reads done before next staging overwrites ktv/mt/p_s
    }

    // ---- write split partials ----
    #pragma unroll
    for (int x = 0; x < 8; ++x) {
        size_t base = ((size_t)sp * n_rows + r0 + rg + x) * 64;
        pO[base + cg] = o0[x];
        pO[base + cg + 32] = o1[x];
    }
    if (t < 64) {
        pM[(size_t)sp * n_rows + r0 + t] = mrow[t];
        pL[(size_t)sp * n_rows + r0 + t] = lrow[t];
    }
}

// ---------------- merge split partials ----------------
template <typename FT>
__global__ __launch_bounds__(64) void attn_merge(
    const int* __restrict__ dflag, int want,
    const float* __restrict__ pO, const float* __restrict__ pM, const float* __restrict__ pL,
    FT* __restrict__ out, int n_rows, int nsplit)
{
    if (*dflag != want) return;
    int r = blockIdx.x;
    int d = threadIdx.x;
    float mstar = -1e30f;
    for (int s = 0; s < nsplit; ++s) mstar = fmaxf(mstar, pM[(size_t)s * n_rows + r]);
    float L = 0.f, O = 0.f;
    for (int s = 0; s < nsplit; ++s) {
        float w = __expf(pM[(size_t)s * n_rows + r] - mstar);
        L += pL[(size_t)s * n_rows + r] * w;
        O += pO[((size_t)s * n_rows + r) * 64 + d] * w;
    }
    stf(out, (size_t)r * 64 + d, O / L);
}

// ---------------- per-row attention (tier-2 fallback only) ----------------
template <typename FT, typename KT>
__global__ __launch_bounds__(256) void attn_row_kernel(
    const int* __restrict__ dflag, int want,
    const FT* __restrict__ h, const FT* __restrict__ qw,
    const KT* __restrict__ k, const KT* __restrict__ v,
    const FT* __restrict__ mask, long mrs, long mcs,
    FT* __restrict__ out, int n_cols)
{
    if (*dflag != want) return;
    int row = blockIdx.x;
    int tid = threadIdx.x;
    extern __shared__ float sc[];
    __shared__ float hrow[64];
    __shared__ float qrow[64];
    __shared__ float red[4];
    __shared__ float opart[4][64];

    if (tid < 64) hrow[tid] = ldf(h, (size_t)row * 64 + tid);
    __syncthreads();
    if (tid < 64) {
        float a = 0.f;
        #pragma unroll 8
        for (int i = 0; i < 64; ++i) a += hrow[i] * ldf(qw, i * 64 + tid);
        qrow[tid] = a > 0.f ? a : 0.01f * a;
    }
    __syncthreads();

    float lmax = -1e30f;
    for (int c = tid; c < n_cols; c += 256) {
        const KT* kr = k + (size_t)c * 64;
        float s = 0.f;
        #pragma unroll 8
        for (int i = 0; i < 64; ++i) s += qrow[i] * ldf(kr, i);
        float m = ldf(mask, (size_t)row * mrs + (size_t)c * mcs);
        s = m * s - 1000.f * (1.f - m);
        sc[c] = s;
        lmax = fmaxf(lmax, s);
    }
    #pragma unroll
    for (int o = 32; o > 0; o >>= 1) lmax = fmaxf(lmax, __shfl_xor(lmax, o, 64));
    int wid = tid >> 6;
    if ((tid & 63) == 0) red[wid] = lmax;
    __syncthreads();
    float bmax = fmaxf(fmaxf(red[0], red[1]), fmaxf(red[2], red[3]));
    __syncthreads();

    float lsum = 0.f;
    for (int c = tid; c < n_cols; c += 256) {
        float e = __expf(sc[c] - bmax);
        sc[c] = e;
        lsum += e;
    }
    lsum = wave_sum(lsum);
    if ((tid & 63) == 0) red[wid] = lsum;
    __syncthreads();
    float inv = 1.f / (red[0] + red[1] + red[2] + red[3]);

    int dd = tid & 63;
    float o = 0.f;
    for (int c = wid; c < n_cols; c += 4) o += sc[c] * ldf(v, (size_t)c * 64 + dd);
    opart[wid][dd] = o;
    __syncthreads();
    if (wid == 0)
        stf(out, (size_t)row * 64 + dd,
            (opart[0][dd] + opart[1][dd] + opart[2][dd] + opart[3][dd]) * inv);
}

// ---------------- node feature update ----------------
template <typename FT>
__global__ __launch_bounds__(64) void node_kernel(
    const int* __restrict__ dflag, int want,
    const FT* __restrict__ h, const float* __restrict__ aggr,
    const float* __restrict__ cnt, const FT* att,  // aliases h_out
    const FT* __restrict__ orig_h,
    const FT* __restrict__ w1, const FT* __restrict__ b1,
    const FT* __restrict__ g, const FT* __restrict__ bt,
    const FT* __restrict__ w2, const FT* __restrict__ b2,
    FT* h_out)
{
    if (*dflag != want) return;
    int node = blockIdx.x;
    int j = threadIdx.x;
    __shared__ float xin[256];
    __shared__ float hbuf[64];
    float invc = 1.f / fmaxf(cnt[node], 1.f);
    float hv = ldf(h, (size_t)node * 64 + j);
    xin[j]       = hv;
    xin[64 + j]  = aggr[(size_t)node * 64 + j] * invc;
    xin[128 + j] = ldf(att, (size_t)node * 64 + j);
    xin[192 + j] = ldf(orig_h, (size_t)node * 64 + j);
    __syncthreads();
    float acc = ldf(b1, j);
    #pragma unroll 4
    for (int i = 0; i < 256; ++i) acc += xin[i] * ldf(w1, i * 64 + j);
    acc = acc > 0.f ? acc : 0.01f * acc;
    float mean = wave_sum(acc) * (1.f / 64.f);
    float cv = acc - mean;
    float var = wave_sum(cv * cv) * (1.f / 64.f);
    float y = cv * rsqrtf(var + 1e-5f) * ldf(g, j) + ldf(bt, j);
    hbuf[j] = y;
    __syncthreads();
    float o = ldf(b2, j);
    #pragma unroll 8
    for (int i = 0; i < 64; ++i) o += hbuf[i] * ldf(w2, i * 64 + j);
    stf(h_out, (size_t)node * 64 + j, 0.5f * o + 0.5f * hv);
}

// ---------------- coordinate output ----------------
template <typename FT>
__global__ void coord_kernel(
    const int* __restrict__ dflag, int want,
    const FT* __restrict__ orig, const FT* __restrict__ coords,
    const float* __restrict__ xacc, const float* __restrict__ cnt,
    FT* __restrict__ out, int n3)
{
    if (*dflag != want) return;
    int i = blockIdx.x * blockDim.x + threadIdx.x;
    if (i >= n3) return;
    int node = i / 3;
    float invc = 1.f / fmaxf(cnt[node], 1.f);
    stf(out, i, 0.25f * ldf(orig, i) + 0.75f * ldf(coords, i) + xacc[i] * invc);
}

// ================= pipeline per dtype =================
template <typename FT, typename KT>
static void run_pipeline(void* const* d_in, void* d_out, int want, int tier,
                         int* dflag, float* aggr_l, float* aggr_r,
                         float* cnt_l, float* cnt_r, float* xacc_l, float* xacc_r,
                         KT* kv_base,
                         float* pO1, float* pM1, float* pL1,
                         float* pO2, float* pM2, float* pL2,
                         unsigned char* m8, unsigned char* m8T,
                         hipStream_t stream)
{
    const FT* coords_lig      = (const FT*)d_in[0];
    const FT* h_lig           = (const FT*)d_in[1];
    const FT* orig_h_lig      = (const FT*)d_in[2];
    const FT* orig_coords_lig = (const FT*)d_in[3];
    const FT* coords_rec      = (const FT*)d_in[4];
    const FT* h_rec           = (const FT*)d_in[5];
    const FT* orig_h_rec      = (const FT*)d_in[6];
    const FT* orig_coords_rec = (const FT*)d_in[7];
    const int* lig_src   = (const int*)d_in[8];
    const int* lig_dst   = (const int*)d_in[9];
    const FT*  lig_efeat = (const FT*)d_in[10];
    const int* rec_src   = (const int*)d_in[11];
    const int* rec_dst   = (const int*)d_in[12];
    const FT*  rec_efeat = (const FT*)d_in[13];
    const FT*  mask      = (const FT*)d_in[14];
    const FT *lig_em_w1 = (const FT*)d_in[15], *lig_em_b1 = (const FT*)d_in[16];
    const FT *lig_em_g  = (const FT*)d_in[17], *lig_em_bt = (const FT*)d_in[18];
    const FT *lig_em_w2 = (const FT*)d_in[19], *lig_em_b2 = (const FT*)d_in[20];
    const FT *rec_em_w1 = (const FT*)d_in[21], *rec_em_b1 = (const FT*)d_in[22];
    const FT *rec_em_g  = (const FT*)d_in[23], *rec_em_bt = (const FT*)d_in[24];
    const FT *rec_em_w2 = (const FT*)d_in[25], *rec_em_b2 = (const FT*)d_in[26];
    const FT *lig_cm_w1 = (const FT*)d_in[27], *lig_cm_b1 = (const FT*)d_in[28];
    const FT *lig_cm_w2 = (const FT*)d_in[29], *lig_cm_b2 = (const FT*)d_in[30];
    const FT *rec_cm_w1 = (const FT*)d_in[31], *rec_cm_b1 = (const FT*)d_in[32];
    const FT *rec_cm_w2 = (const FT*)d_in[33], *rec_cm_b2 = (const FT*)d_in[34];
    const FT *q_lig_w = (const FT*)d_in[35], *k_lig_w = (const FT*)d_in[36];
    const FT *v_lig_w = (const FT*)d_in[37], *q_rec_w = (const FT*)d_in[38];
    const FT *k_rec_w = (const FT*)d_in[39], *v_rec_w = (const FT*)d_in[40];
    const FT *lig_nm_w1 = (const FT*)d_in[41], *lig_nm_b1 = (const FT*)d_in[42];
    const FT *lig_nm_g  = (const FT*)d_in[43], *lig_nm_bt = (const FT*)d_in[44];
    const FT *lig_nm_w2 = (const FT*)d_in[45], *lig_nm_b2 = (const FT*)d_in[46];
    const FT *rec_nm_w1 = (const FT*)d_in[47], *rec_nm_b1 = (const FT*)d_in[48];
    const FT *rec_nm_g  = (const FT*)d_in[49], *rec_nm_bt = (const FT*)d_in[50];
    const FT *rec_nm_w2 = (const FT*)d_in[51], *rec_nm_b2 = (const FT*)d_in[52];

    KT* k_l = kv_base;
    KT* v_l = k_l + (size_t)N_LIG * 64;
    KT* k_r = v_l + (size_t)N_LIG * 64;
    KT* v_r = k_r + (size_t)N_REC * 64;

    FT* out = (FT*)d_out;
    FT* x_lig_o = out;                 // 4096*3
    FT* h_lig_o = out + 12288;         // 4096*64 (att_l parking)
    FT* x_rec_o = out + 274432;        // 8192*3
    FT* h_rec_o = out + 299008;        // 8192*64 (att_r parking)

    // k/v projections
    linear64_kernel<FT, KT><<<N_LIG, 64, 0, stream>>>(dflag, want, h_lig, k_lig_w, k_l, 1);
    linear64_kernel<FT, KT><<<N_LIG, 64, 0, stream>>>(dflag, want, h_lig, v_lig_w, v_l, 0);
    linear64_kernel<FT, KT><<<N_REC, 64, 0, stream>>>(dflag, want, h_rec, k_rec_w, k_r, 1);
    linear64_kernel<FT, KT><<<N_REC, 64, 0, stream>>>(dflag, want, h_rec, v_rec_w, v_r, 0);

    // fused edge kernels
    edge_kernel<FT, F_LIGc><<<E_LIG, 64, 0, stream>>>(dflag, want,
        coords_lig, h_lig, lig_src, lig_dst, lig_efeat,
        lig_em_w1, lig_em_b1, lig_em_g, lig_em_bt, lig_em_w2, lig_em_b2,
        lig_cm_w1, lig_cm_b1, lig_cm_w2, lig_cm_b2,
        aggr_l, cnt_l, xacc_l);
    edge_kernel<FT, F_RECc><<<E_REC, 64, 0, stream>>>(dflag, want,
        coords_rec, h_rec, rec_src, rec_dst, rec_efeat,
        rec_em_w1, rec_em_b1, rec_em_g, rec_em_bt, rec_em_w2, rec_em_b2,
        rec_cm_w1, rec_cm_b1, rec_cm_w2, rec_cm_b2,
        aggr_r, cnt_r, xacc_r);

    // attention
    if (tier <= 1) {
        if (tier == 0) {
            dim3 bg(N_REC / 64, N_LIG / 64);
            build_masks<FT><<<bg, 256, 0, stream>>>(dflag, want, mask, m8, m8T, N_LIG, N_REC);
            attn_tiled<FT, KT, 0><<<(N_LIG / 64) * 4, 256, 0, stream>>>(dflag, want,
                h_lig, q_lig_w, k_r, v_r, m8, mask, 0L, 0L,
                pO1, pM1, pL1, N_LIG, N_REC, 4);
            attn_tiled<FT, KT, 0><<<(N_REC / 64) * 2, 256, 0, stream>>>(dflag, want,
                h_rec, q_rec_w, k_l, v_l, m8T, mask, 0L, 0L,
                pO2, pM2, pL2, N_REC, N_LIG, 2);
        } else {
            attn_tiled<FT, KT, 1><<<(N_LIG / 64) * 4, 256, 0, stream>>>(dflag, want,
                h_lig, q_lig_w, k_r, v_r, (const unsigned char*)0, mask, (long)N_REC, 1L,
                pO1, pM1, pL1, N_LIG, N_REC, 4);
            attn_tiled<FT, KT, 1><<<(N_REC / 64) * 2, 256, 0, stream>>>(dflag, want,
                h_rec, q_rec_w, k_l, v_l, (const unsigned char*)0, mask, 1L, (long)N_REC,
                pO2, pM2, pL2, N_REC, N_LIG, 2);
        }
        attn_merge<FT><<<N_LIG, 64, 0, stream>>>(dflag, want, pO1, pM1, pL1, h_lig_o, N_LIG, 4);
        attn_merge<FT><<<N_REC, 64, 0, stream>>>(dflag, want, pO2, pM2, pL2, h_rec_o, N_REC, 2);
    } else {
        attn_row_kernel<FT, KT><<<N_LIG, 256, N_REC * sizeof(float), stream>>>(dflag, want,
            h_lig, q_lig_w, k_r, v_r, mask, (long)N_REC, 1L, h_lig_o, N_REC);
        attn_row_kernel<FT, KT><<<N_REC, 256, N_LIG * sizeof(float), stream>>>(dflag, want,
            h_rec, q_rec_w, k_l, v_l, mask, 1L, (long)N_REC, h_rec_o, N_LIG);
    }

    // node updates
    node_kernel<FT><<<N_LIG, 64, 0, stream>>>(dflag, want,
        h_lig, aggr_l, cnt_l, h_lig_o, orig_h_lig,
        lig_nm_w1, lig_nm_b1, lig_nm_g, lig_nm_bt, lig_nm_w2, lig_nm_b2, h_lig_o);
    node_kernel<FT><<<N_REC, 64, 0, stream>>>(dflag, want,
        h_rec, aggr_r, cnt_r, h_rec_o, orig_h_rec,
        rec_nm_w1, rec_nm_b1, rec_nm_g, rec_nm_bt, rec_nm_w2, rec_nm_b2, h_rec_o);

    // coordinate outputs
    coord_kernel<FT><<<(N_LIG * 3 + 255) / 256, 256, 0, stream>>>(dflag, want,
        orig_coords_lig, coords_lig, xacc_l, cnt_l, x_lig_o, N_LIG * 3);
    coord_kernel<FT><<<(N_REC * 3 + 255) / 256, 256, 0, stream>>>(dflag, want,
        orig_coords_rec, coords_rec, xacc_r, cnt_r, x_rec_o, N_REC * 3);
}

extern "C" void kernel_launch(void* const* d_in, const int* in_sizes, int n_in,
                              void* d_out, int out_size, void* d_ws, size_t ws_size,
                              hipStream_t stream)
{
    char* wsb = (char*)d_ws;
    int* dflag = (int*)wsb;                          // 16 B slot
    float* aggr_l = (float*)(wsb + 16);
    float* aggr_r = aggr_l + (size_t)N_LIG * 64;
    float* cnt_l  = aggr_r + (size_t)N_REC * 64;
    float* cnt_r  = cnt_l + N_LIG;
    float* xacc_l = cnt_r + N_REC;
    float* xacc_r = xacc_l + (size_t)N_LIG * 3;
    const size_t zero_floats =
        (size_t)N_LIG * 64 + (size_t)N_REC * 64 + N_LIG + N_REC + N_LIG * 3 + N_REC * 3;
    const size_t core_b = 16 + zero_floats * 4;                      // 3,342,352
    const size_t kvf32_b  = (size_t)(N_LIG + N_REC) * 64 * 2 * 4;    // 6,291,456
    const size_t kvbf16_b = kvf32_b / 2;
    const size_t part_b = ((size_t)4 * N_LIG * 64 + (size_t)2 * N_REC * 64) * 4
                        + ((size_t)4 * N_LIG + (size_t)2 * N_REC) * 2 * 4;  // 8,650,752
    const size_t m8_b = (size_t)N_LIG * N_REC;                       // 33,554,432

    int tier;
    if (ws_size >= core_b + kvf32_b + part_b + 2 * m8_b) tier = 0;
    else if (ws_size >= core_b + kvf32_b + part_b) tier = 1;
    else tier = 2;

    char* kv_base = wsb + core_b;
    size_t kv_b = (tier <= 1) ? kvf32_b : kvbf16_b;
    float* pO1 = (float*)(kv_base + kv_b);
    float* pO2 = pO1 + (size_t)4 * N_LIG * 64;
    float* pM1 = pO2 + (size_t)2 * N_REC * 64;
    float* pL1 = pM1 + (size_t)4 * N_LIG;
    float* pM2 = pL1 + (size_t)4 * N_LIG;
    float* pL2 = pM2 + (size_t)2 * N_REC;
    unsigned char* m8  = (unsigned char*)(kv_base + kv_b + part_b);
    unsigned char* m8T = m8 + m8_b;

    detect_kernel<<<1, 256, 0, stream>>>((const unsigned*)d_in[14], dflag);
    zero_kernel<<<((int)zero_floats + 255) / 256, 256, 0, stream>>>(aggr_l, (int)zero_floats);

    if (tier <= 1) {
        run_pipeline<float, float>(d_in, d_out, 0, tier, dflag, aggr_l, aggr_r,
                                   cnt_l, cnt_r, xacc_l, xacc_r, (float*)kv_base,
                                   pO1, pM1, pL1, pO2, pM2, pL2, m8, m8T, stream);
        run_pipeline<bf16, float>(d_in, d_out, 1, tier, dflag, aggr_l, aggr_r,
                                  cnt_l, cnt_r, xacc_l, xacc_r, (float*)kv_base,
                                  pO1, pM1, pL1, pO2, pM2, pL2, m8, m8T, stream);
    } else {
        run_pipeline<float, bf16>(d_in, d_out, 0, tier, dflag, aggr_l, aggr_r,
                                  cnt_l, cnt_r, xacc_l, xacc_r, (bf16*)kv_base,
                                  pO1, pM1, pL1, pO2, pM2, pL2, m8, m8T, stream);
        run_pipeline<bf16, bf16>(d_in, d_out, 1, tier, dflag, aggr_l, aggr_r,
                                 cnt_l, cnt_r, xacc_l, xacc_r, (bf16*)kv_base,
                                 pO1, pM1, pL1, pO2, pM2, pL2, m8, m8T, stream);
    }
}

// Round 6
// 1766.468 us; speedup vs baseline: 3.8829x; 1.2915x over previous
//
#include <hip/hip_runtime.h>
#include <hip/hip_bf16.h>

typedef __hip_bfloat16 bf16;

#define N_LIG 4096
#define N_REC 8192
#define E_LIG 65536
#define E_REC 262144
#define F_LIGc 15
#define F_RECc 27

__device__ __forceinline__ void stf(float* p, size_t i, float v) { p[i] = v; }
__device__ __forceinline__ void stf(bf16* p, size_t i, float v) { p[i] = __float2bfloat16(v); }
__device__ __forceinline__ float ldkv(const float* p, size_t i) { return p[i]; }
__device__ __forceinline__ float ldkv(const bf16* p, size_t i) { return __bfloat162float(p[i]); }

__constant__ float c_inv_sigma[15] = {
    1.0f, 0.6666666667f, 0.4444444444f, 0.2962962963f, 0.1975308642f,
    0.1316872428f, 0.08779149520f, 0.05852766346f, 0.03901844231f,
    0.02601229487f, 0.01734152992f, 0.01156101994f, 0.007707346628f,
    0.005138231085f, 0.003425487390f};

__device__ __forceinline__ float wave_sum(float v) {
    #pragma unroll
    for (int o = 32; o > 0; o >>= 1) v += __shfl_xor(v, o, 64);
    return v;
}

__device__ __forceinline__ unsigned pack_bf2(float a, float b) {
    bf16 ba = __float2bfloat16(a), bb = __float2bfloat16(b);
    unsigned short ua = *(unsigned short*)&ba, ub = *(unsigned short*)&bb;
    return (unsigned)ua | ((unsigned)ub << 16);
}

__global__ void zero_kernel(float* __restrict__ p, int n) {
    int i = blockIdx.x * blockDim.x + threadIdx.x;
    if (i < n) p[i] = 0.f;
}

// ---------------- edge kernel v2: LDS-staged weights, 64 edges/block ----------------
// block = 256 threads (4 waves); each wave processes EPB/4 edges serially.
// Weights staged once per block as packed bf16 pairs (i, i+1) per output channel.
template <int F, int EPB>
__global__ __launch_bounds__(256) void edge_kernel2(
    const float* __restrict__ coords, const float* __restrict__ h,
    const int* __restrict__ src, const int* __restrict__ dst,
    const float* __restrict__ efeat,
    const float* __restrict__ w1, const float* __restrict__ b1,
    const float* __restrict__ g, const float* __restrict__ bt,
    const float* __restrict__ w2, const float* __restrict__ b2,
    const float* __restrict__ cw1, const float* __restrict__ cb1,
    const float* __restrict__ cw2, const float* __restrict__ cb2,
    float* __restrict__ aggr, float* __restrict__ cnt, float* __restrict__ xacc)
{
    constexpr int IN = 128 + F + 15;   // 158 (lig) / 170 (rec), even
    constexpr int IN2 = IN / 2;
    __shared__ unsigned w1p[IN2 * 64];
    __shared__ unsigned w2p[32 * 64];
    __shared__ unsigned cw1p[32 * 64];
    __shared__ float b1s[64], gs[64], bts[64], b2s[64], cb1s[64], cw2s[64];
    __shared__ float cb2s0;
    __shared__ float xin[4][IN];
    __shared__ float hbuf[4][64];
    __shared__ float msgs[4][64];
    __shared__ float xrs[4][3];

    const int t = threadIdx.x;
    for (int idx = t; idx < IN2 * 64; idx += 256) {
        int i2 = idx >> 6, j = idx & 63;
        w1p[idx] = pack_bf2(w1[(2 * i2) * 64 + j], w1[(2 * i2 + 1) * 64 + j]);
    }
    for (int idx = t; idx < 32 * 64; idx += 256) {
        int i2 = idx >> 6, j = idx & 63;
        w2p[idx]  = pack_bf2(w2[(2 * i2) * 64 + j],  w2[(2 * i2 + 1) * 64 + j]);
        cw1p[idx] = pack_bf2(cw1[(2 * i2) * 64 + j], cw1[(2 * i2 + 1) * 64 + j]);
    }
    if (t < 64) {
        b1s[t] = b1[t]; gs[t] = g[t]; bts[t] = bt[t];
        b2s[t] = b2[t]; cb1s[t] = cb1[t]; cw2s[t] = cw2[t];
    }
    if (t == 0) cb2s0 = cb2[0];
    __syncthreads();

    const int w = t >> 6, j = t & 63;
    constexpr int PERW = EPB / 4;
    float* xw = xin[w];

    for (int it = 0; it < PERW; ++it) {
        int e = blockIdx.x * EPB + w * PERW + it;
        int s = src[e], d = dst[e];
        // stage per-edge inputs (per-wave LDS; wave-internal ordering, no barrier)
        xw[j]      = h[(size_t)s * 64 + j];
        xw[64 + j] = h[(size_t)d * 64 + j];
        if (j < F) xw[128 + j] = efeat[(size_t)e * F + j];
        if (j < 3) xrs[w][j] = coords[s * 3 + j] - coords[d * 3 + j];
        float xr0 = xrs[w][0], xr1 = xrs[w][1], xr2 = xrs[w][2];
        float d2 = xr0 * xr0 + xr1 * xr1 + xr2 * xr2;
        if (j < 15) xw[128 + F + j] = __expf(-d2 * c_inv_sigma[j]);

        // layer 1: acc = b1 + xin . w1[:,j]
        float acc = b1s[j];
        for (int i2 = 0; i2 < IN2; ++i2) {
            unsigned u = w1p[i2 * 64 + j];
            float2 x2 = *(const float2*)&xw[2 * i2];
            acc = fmaf(__uint_as_float(u << 16), x2.x, acc);
            acc = fmaf(__uint_as_float(u & 0xffff0000u), x2.y, acc);
        }
        acc = acc > 0.f ? acc : 0.01f * acc;
        float mean = wave_sum(acc) * (1.f / 64.f);
        float cv = acc - mean;
        float var = wave_sum(cv * cv) * (1.f / 64.f);
        float y = cv * rsqrtf(var + 1e-5f) * gs[j] + bts[j];
        hbuf[w][j] = y;

        // layer 2: msg
        float msg = b2s[j];
        for (int i2 = 0; i2 < 32; ++i2) {
            unsigned u = w2p[i2 * 64 + j];
            float2 h2 = *(const float2*)&hbuf[w][2 * i2];
            msg = fmaf(__uint_as_float(u << 16), h2.x, msg);
            msg = fmaf(__uint_as_float(u & 0xffff0000u), h2.y, msg);
        }
        msgs[w][j] = msg;

        // coords mlp
        float tt = cb1s[j];
        for (int i2 = 0; i2 < 32; ++i2) {
            unsigned u = cw1p[i2 * 64 + j];
            float2 m2 = *(const float2*)&msgs[w][2 * i2];
            tt = fmaf(__uint_as_float(u << 16), m2.x, tt);
            tt = fmaf(__uint_as_float(u & 0xffff0000u), m2.y, tt);
        }
        tt = tt > 0.f ? tt : 0.01f * tt;
        float coef = wave_sum(tt * cw2s[j]) + cb2s0;

        atomicAdd(&aggr[(size_t)d * 64 + j], msg);
        if (j == 0) atomicAdd(&cnt[d], 1.0f);
        if (j < 3) atomicAdd(&xacc[d * 3 + j], xrs[w][j] * coef);
    }
}

// ---------------- k/v projection ----------------
template <typename OT>
__global__ __launch_bounds__(64) void linear64_kernel(
    const float* __restrict__ h, const float* __restrict__ w,
    OT* __restrict__ out, int do_lrelu)
{
    int node = blockIdx.x;
    int j = threadIdx.x;
    __shared__ float x[64];
    x[j] = h[(size_t)node * 64 + j];
    __syncthreads();
    float acc = 0.f;
    #pragma unroll 8
    for (int i = 0; i < 64; ++i) acc += x[i] * w[i * 64 + j];
    if (do_lrelu) acc = acc > 0.f ? acc : 0.01f * acc;
    stf(out, (size_t)node * 64 + j, acc);
}

// ---------------- u8 mask build: m8[r][c], m8T[c][r] ----------------
__global__ __launch_bounds__(256) void build_masks(
    const float* __restrict__ mask, unsigned char* __restrict__ m8,
    unsigned char* __restrict__ m8T, int R, int C)
{
    __shared__ __align__(16) unsigned char tl[64 * 80];
    int r0 = blockIdx.y * 64, c0 = blockIdx.x * 64;
    int t = threadIdx.x;
    int cs = (t & 15) * 4;
    #pragma unroll
    for (int rr = 0; rr < 4; ++rr) {
        int r = (t >> 4) + rr * 16;
        unsigned b0 = (mask[(size_t)(r0 + r) * C + c0 + cs + 0] != 0.f);
        unsigned b1 = (mask[(size_t)(r0 + r) * C + c0 + cs + 1] != 0.f);
        unsigned b2 = (mask[(size_t)(r0 + r) * C + c0 + cs + 2] != 0.f);
        unsigned b3 = (mask[(size_t)(r0 + r) * C + c0 + cs + 3] != 0.f);
        *(unsigned*)&m8[(size_t)(r0 + r) * C + c0 + cs] = b0 | (b1 << 8) | (b2 << 16) | (b3 << 24);
        tl[(cs + 0) * 80 + r] = (unsigned char)b0;
        tl[(cs + 1) * 80 + r] = (unsigned char)b1;
        tl[(cs + 2) * 80 + r] = (unsigned char)b2;
        tl[(cs + 3) * 80 + r] = (unsigned char)b3;
    }
    __syncthreads();
    {
        int c = t >> 2, rs = (t & 3) * 16;
        *(uint4*)&m8T[(size_t)(c0 + c) * R + r0 + rs] = *(const uint4*)&tl[c * 80 + rs];
    }
}

// ---------------- tiled masked flash attention with column splits ----------------
template <int MMODE>  // 0: u8 mask, 1: strided f32 mask
__global__ __launch_bounds__(256) void attn_tiled(
    const float* __restrict__ h, const float* __restrict__ qw,
    const float* __restrict__ kk, const float* __restrict__ vv,
    const unsigned char* __restrict__ m8,
    const float* __restrict__ maskf, long mrs, long mcs,
    float* __restrict__ pO, float* __restrict__ pM, float* __restrict__ pL,
    int n_rows, int n_cols, int nsplit)
{
    const int t = threadIdx.x;
    const int rb = blockIdx.x / nsplit;
    const int sp = blockIdx.x - rb * nsplit;
    const int r0 = rb * 64;
    const int cols_per = n_cols / nsplit;
    const int c_begin = sp * cols_per;

    __shared__ __align__(16) float q_s[64 * 68];
    __shared__ __align__(16) float ktv[64 * 68];
    __shared__ __align__(16) float p_s[64 * 68];
    __shared__ float mrow[64], lrow[64], anew[64], mnew[64];
    __shared__ float lpart[256];
    __shared__ __align__(16) unsigned char mt[4096];

    const int cg = t & 31;
    const int rg = (t >> 5) * 8;

    for (int u = 0; u < 16; ++u) {
        int i = t + 256 * u;
        int r = i >> 6, d = i & 63;
        p_s[r * 68 + d] = h[(size_t)(r0 + r) * 64 + d];
        ktv[d * 68 + r] = qw[(size_t)r * 64 + d];
    }
    __syncthreads();
    {
        float a0[8], a1[8];
        #pragma unroll
        for (int x = 0; x < 8; ++x) { a0[x] = 0.f; a1[x] = 0.f; }
        for (int d = 0; d < 64; d += 4) {
            float4 b0 = *(const float4*)&ktv[cg * 68 + d];
            float4 b1 = *(const float4*)&ktv[(cg + 32) * 68 + d];
            #pragma unroll
            for (int x = 0; x < 8; ++x) {
                float4 a = *(const float4*)&p_s[(rg + x) * 68 + d];
                a0[x] += a.x * b0.x + a.y * b0.y + a.z * b0.z + a.w * b0.w;
                a1[x] += a.x * b1.x + a.y * b1.y + a.z * b1.z + a.w * b1.w;
            }
        }
        __syncthreads();
        #pragma unroll
        for (int x = 0; x < 8; ++x) {
            float v0 = a0[x]; v0 = v0 > 0.f ? v0 : 0.01f * v0;
            float v1 = a1[x]; v1 = v1 > 0.f ? v1 : 0.01f * v1;
            q_s[(rg + x) * 68 + cg] = v0;
            q_s[(rg + x) * 68 + cg + 32] = v1;
        }
    }
    if (t < 64) { mrow[t] = -1e30f; lrow[t] = 0.f; }
    float o0[8], o1[8];
    #pragma unroll
    for (int x = 0; x < 8; ++x) { o0[x] = 0.f; o1[x] = 0.f; }
    __syncthreads();

    for (int c0 = c_begin; c0 < c_begin + cols_per; c0 += 64) {
        #pragma unroll
        for (int u = 0; u < 4; ++u) {
            int i4 = (t + 256 * u) * 4;
            int c = i4 >> 6, d = i4 & 63;
            *(float4*)&ktv[c * 68 + d] = *(const float4*)&kk[(size_t)(c0 + c) * 64 + d];
        }
        if (MMODE == 0) {
            int r = t >> 2, seg = (t & 3) * 16;
            *(uint4*)&mt[r * 64 + seg] =
                *(const uint4*)&m8[(size_t)(r0 + r) * n_cols + c0 + seg];
        } else {
            #pragma unroll
            for (int u = 0; u < 16; ++u) {
                int i = t + 256 * u;
                int r = i >> 6, c = i & 63;
                mt[r * 64 + c] = (unsigned char)(
                    maskf[(size_t)(r0 + r) * mrs + (size_t)(c0 + c) * mcs] != 0.f);
            }
        }
        __syncthreads();

        {
            float s0[8], s1[8];
            #pragma unroll
            for (int x = 0; x < 8; ++x) { s0[x] = 0.f; s1[x] = 0.f; }
            for (int d = 0; d < 64; d += 4) {
                float4 b0 = *(const float4*)&ktv[cg * 68 + d];
                float4 b1 = *(const float4*)&ktv[(cg + 32) * 68 + d];
                #pragma unroll
                for (int x = 0; x < 8; ++x) {
                    float4 a = *(const float4*)&q_s[(rg + x) * 68 + d];
                    s0[x] += a.x * b0.x + a.y * b0.y + a.z * b0.z + a.w * b0.w;
                    s1[x] += a.x * b1.x + a.y * b1.y + a.z * b1.z + a.w * b1.w;
                }
            }
            #pragma unroll
            for (int x = 0; x < 8; ++x) {
                int r = rg + x;
                p_s[r * 68 + cg]      = mt[r * 64 + cg]      ? s0[x] : -1000.f;
                p_s[r * 68 + cg + 32] = mt[r * 64 + cg + 32] ? s1[x] : -1000.f;
            }
        }
        __syncthreads();

        #pragma unroll
        for (int u = 0; u < 4; ++u) {
            int i4 = (t + 256 * u) * 4;
            int c = i4 >> 6, d = i4 & 63;
            float4 v4 = *(const float4*)&vv[(size_t)(c0 + c) * 64 + d];
            ktv[(d + 0) * 68 + c] = v4.x;
            ktv[(d + 1) * 68 + c] = v4.y;
            ktv[(d + 2) * 68 + c] = v4.z;
            ktv[(d + 3) * 68 + c] = v4.w;
        }
        if (t < 64) {
            float mx = -1e30f;
            for (int c = 0; c < 64; c += 4) {
                float4 s4 = *(const float4*)&p_s[t * 68 + c];
                mx = fmaxf(mx, fmaxf(fmaxf(s4.x, s4.y), fmaxf(s4.z, s4.w)));
            }
            float mn = fmaxf(mrow[t], mx);
            mnew[t] = mn;
            anew[t] = __expf(mrow[t] - mn);
            mrow[t] = mn;
        }
        __syncthreads();

        {
            int r = t >> 2, seg = (t & 3) * 16;
            float mr = mnew[r];
            float ps = 0.f;
            #pragma unroll
            for (int c = seg; c < seg + 16; c += 4) {
                float4 s4 = *(float4*)&p_s[r * 68 + c];
                s4.x = __expf(s4.x - mr);
                s4.y = __expf(s4.y - mr);
                s4.z = __expf(s4.z - mr);
                s4.w = __expf(s4.w - mr);
                ps += s4.x + s4.y + s4.z + s4.w;
                *(float4*)&p_s[r * 68 + c] = s4;
            }
            lpart[t] = ps;
        }
        __syncthreads();
        if (t < 64)
            lrow[t] = lrow[t] * anew[t] +
                      lpart[t * 4] + lpart[t * 4 + 1] + lpart[t * 4 + 2] + lpart[t * 4 + 3];

        {
            #pragma unroll
            for (int x = 0; x < 8; ++x) {
                float a = anew[rg + x];
                o0[x] *= a;
                o1[x] *= a;
            }
            for (int c = 0; c < 64; c += 4) {
                float4 b0 = *(const float4*)&ktv[cg * 68 + c];
                float4 b1 = *(const float4*)&ktv[(cg + 32) * 68 + c];
                #pragma unroll
                for (int x = 0; x < 8; ++x) {
                    float4 p = *(const float4*)&p_s[(rg + x) * 68 + c];
                    o0[x] += p.x * b0.x + p.y * b0.y + p.z * b0.z + p.w * b0.w;
                    o1[x] += p.x * b1.x + p.y * b1.y + p.z * b1.z + p.w * b1.w;
                }
            }
        }
        __syncthreads();
    }

    #pragma unroll
    for (int x = 0; x < 8; ++x) {
        size_t base = ((size_t)sp * n_rows + r0 + rg + x) * 64;
        pO[base + cg] = o0[x];
        pO[base + cg + 32] = o1[x];
    }
    if (t < 64) {
        pM[(size_t)sp * n_rows + r0 + t] = mrow[t];
        pL[(size_t)sp * n_rows + r0 + t] = lrow[t];
    }
}

// ---------------- merge split partials ----------------
__global__ __launch_bounds__(64) void attn_merge(
    const float* __restrict__ pO, const float* __restrict__ pM, const float* __restrict__ pL,
    float* __restrict__ out, int n_rows, int nsplit)
{
    int r = blockIdx.x;
    int d = threadIdx.x;
    float mstar = -1e30f;
    for (int s = 0; s < nsplit; ++s) mstar = fmaxf(mstar, pM[(size_t)s * n_rows + r]);
    float L = 0.f, O = 0.f;
    for (int s = 0; s < nsplit; ++s) {
        float w = __expf(pM[(size_t)s * n_rows + r] - mstar);
        L += pL[(size_t)s * n_rows + r] * w;
        O += pO[((size_t)s * n_rows + r) * 64 + d] * w;
    }
    out[(size_t)r * 64 + d] = O / L;
}

// ---------------- per-row attention (tier-2 fallback) ----------------
template <typename KT>
__global__ __launch_bounds__(256) void attn_row_kernel(
    const float* __restrict__ h, const float* __restrict__ qw,
    const KT* __restrict__ k, const KT* __restrict__ v,
    const float* __restrict__ mask, long mrs, long mcs,
    float* __restrict__ out, int n_cols)
{
    int row = blockIdx.x;
    int tid = threadIdx.x;
    extern __shared__ float sc[];
    __shared__ float hrow[64];
    __shared__ float qrow[64];
    __shared__ float red[4];
    __shared__ float opart[4][64];

    if (tid < 64) hrow[tid] = h[(size_t)row * 64 + tid];
    __syncthreads();
    if (tid < 64) {
        float a = 0.f;
        #pragma unroll 8
        for (int i = 0; i < 64; ++i) a += hrow[i] * qw[i * 64 + tid];
        qrow[tid] = a > 0.f ? a : 0.01f * a;
    }
    __syncthreads();

    float lmax = -1e30f;
    for (int c = tid; c < n_cols; c += 256) {
        const KT* kr = k + (size_t)c * 64;
        float s = 0.f;
        #pragma unroll 8
        for (int i = 0; i < 64; ++i) s += qrow[i] * ldkv(kr, i);
        float m = mask[(size_t)row * mrs + (size_t)c * mcs];
        s = m * s - 1000.f * (1.f - m);
        sc[c] = s;
        lmax = fmaxf(lmax, s);
    }
    #pragma unroll
    for (int o = 32; o > 0; o >>= 1) lmax = fmaxf(lmax, __shfl_xor(lmax, o, 64));
    int wid = tid >> 6;
    if ((tid & 63) == 0) red[wid] = lmax;
    __syncthreads();
    float bmax = fmaxf(fmaxf(red[0], red[1]), fmaxf(red[2], red[3]));
    __syncthreads();

    float lsum = 0.f;
    for (int c = tid; c < n_cols; c += 256) {
        float e = __expf(sc[c] - bmax);
        sc[c] = e;
        lsum += e;
    }
    lsum = wave_sum(lsum);
    if ((tid & 63) == 0) red[wid] = lsum;
    __syncthreads();
    float inv = 1.f / (red[0] + red[1] + red[2] + red[3]);

    int dd = tid & 63;
    float o = 0.f;
    for (int c = wid; c < n_cols; c += 4) o += sc[c] * ldkv(v, (size_t)c * 64 + dd);
    opart[wid][dd] = o;
    __syncthreads();
    if (wid == 0)
        out[(size_t)row * 64 + dd] =
            (opart[0][dd] + opart[1][dd] + opart[2][dd] + opart[3][dd]) * inv;
}

// ---------------- node feature update ----------------
__global__ __launch_bounds__(64) void node_kernel(
    const float* __restrict__ h, const float* __restrict__ aggr,
    const float* __restrict__ cnt, const float* att,  // aliases h_out
    const float* __restrict__ orig_h,
    const float* __restrict__ w1, const float* __restrict__ b1,
    const float* __restrict__ g, const float* __restrict__ bt,
    const float* __restrict__ w2, const float* __restrict__ b2,
    float* h_out)
{
    int node = blockIdx.x;
    int j = threadIdx.x;
    __shared__ float xin[256];
    __shared__ float hbuf[64];
    float invc = 1.f / fmaxf(cnt[node], 1.f);
    float hv = h[(size_t)node * 64 + j];
    xin[j]       = hv;
    xin[64 + j]  = aggr[(size_t)node * 64 + j] * invc;
    xin[128 + j] = att[(size_t)node * 64 + j];
    xin[192 + j] = orig_h[(size_t)node * 64 + j];
    __syncthreads();
    float acc = b1[j];
    #pragma unroll 4
    for (int i = 0; i < 256; ++i) acc += xin[i] * w1[i * 64 + j];
    acc = acc > 0.f ? acc : 0.01f * acc;
    float mean = wave_sum(acc) * (1.f / 64.f);
    float cv = acc - mean;
    float var = wave_sum(cv * cv) * (1.f / 64.f);
    float y = cv * rsqrtf(var + 1e-5f) * g[j] + bt[j];
    hbuf[j] = y;
    __syncthreads();
    float o = b2[j];
    #pragma unroll 8
    for (int i = 0; i < 64; ++i) o += hbuf[i] * w2[i * 64 + j];
    h_out[(size_t)node * 64 + j] = 0.5f * o + 0.5f * hv;
}

// ---------------- coordinate output ----------------
__global__ void coord_kernel(
    const float* __restrict__ orig, const float* __restrict__ coords,
    const float* __restrict__ xacc, const float* __restrict__ cnt,
    float* __restrict__ out, int n3)
{
    int i = blockIdx.x * blockDim.x + threadIdx.x;
    if (i >= n3) return;
    int node = i / 3;
    float invc = 1.f / fmaxf(cnt[node], 1.f);
    out[i] = 0.25f * orig[i] + 0.75f * coords[i] + xacc[i] * invc;
}

extern "C" void kernel_launch(void* const* d_in, const int* in_sizes, int n_in,
                              void* d_out, int out_size, void* d_ws, size_t ws_size,
                              hipStream_t stream)
{
    const float* coords_lig      = (const float*)d_in[0];
    const float* h_lig           = (const float*)d_in[1];
    const float* orig_h_lig      = (const float*)d_in[2];
    const float* orig_coords_lig = (const float*)d_in[3];
    const float* coords_rec      = (const float*)d_in[4];
    const float* h_rec           = (const float*)d_in[5];
    const float* orig_h_rec      = (const float*)d_in[6];
    const float* orig_coords_rec = (const float*)d_in[7];
    const int* lig_src   = (const int*)d_in[8];
    const int* lig_dst   = (const int*)d_in[9];
    const float* lig_efeat = (const float*)d_in[10];
    const int* rec_src   = (const int*)d_in[11];
    const int* rec_dst   = (const int*)d_in[12];
    const float* rec_efeat = (const float*)d_in[13];
    const float* mask      = (const float*)d_in[14];
    const float *lig_em_w1 = (const float*)d_in[15], *lig_em_b1 = (const float*)d_in[16];
    const float *lig_em_g  = (const float*)d_in[17], *lig_em_bt = (const float*)d_in[18];
    const float *lig_em_w2 = (const float*)d_in[19], *lig_em_b2 = (const float*)d_in[20];
    const float *rec_em_w1 = (const float*)d_in[21], *rec_em_b1 = (const float*)d_in[22];
    const float *rec_em_g  = (const float*)d_in[23], *rec_em_bt = (const float*)d_in[24];
    const float *rec_em_w2 = (const float*)d_in[25], *rec_em_b2 = (const float*)d_in[26];
    const float *lig_cm_w1 = (const float*)d_in[27], *lig_cm_b1 = (const float*)d_in[28];
    const float *lig_cm_w2 = (const float*)d_in[29], *lig_cm_b2 = (const float*)d_in[30];
    const float *rec_cm_w1 = (const float*)d_in[31], *rec_cm_b1 = (const float*)d_in[32];
    const float *rec_cm_w2 = (const float*)d_in[33], *rec_cm_b2 = (const float*)d_in[34];
    const float *q_lig_w = (const float*)d_in[35], *k_lig_w = (const float*)d_in[36];
    const float *v_lig_w = (const float*)d_in[37], *q_rec_w = (const float*)d_in[38];
    const float *k_rec_w = (const float*)d_in[39], *v_rec_w = (const float*)d_in[40];
    const float *lig_nm_w1 = (const float*)d_in[41], *lig_nm_b1 = (const float*)d_in[42];
    const float *lig_nm_g  = (const float*)d_in[43], *lig_nm_bt = (const float*)d_in[44];
    const float *lig_nm_w2 = (const float*)d_in[45], *lig_nm_b2 = (const float*)d_in[46];
    const float *rec_nm_w1 = (const float*)d_in[47], *rec_nm_b1 = (const float*)d_in[48];
    const float *rec_nm_g  = (const float*)d_in[49], *rec_nm_bt = (const float*)d_in[50];
    const float *rec_nm_w2 = (const float*)d_in[51], *rec_nm_b2 = (const float*)d_in[52];

    char* wsb = (char*)d_ws;
    float* aggr_l = (float*)(wsb + 16);
    float* aggr_r = aggr_l + (size_t)N_LIG * 64;
    float* cnt_l  = aggr_r + (size_t)N_REC * 64;
    float* cnt_r  = cnt_l + N_LIG;
    float* xacc_l = cnt_r + N_REC;
    float* xacc_r = xacc_l + (size_t)N_LIG * 3;
    const size_t zero_floats =
        (size_t)N_LIG * 64 + (size_t)N_REC * 64 + N_LIG + N_REC + N_LIG * 3 + N_REC * 3;
    const size_t core_b = 16 + zero_floats * 4;
    const size_t kvf32_b  = (size_t)(N_LIG + N_REC) * 64 * 2 * 4;
    const size_t kvbf16_b = kvf32_b / 2;
    const size_t part_b = ((size_t)4 * N_LIG * 64 + (size_t)2 * N_REC * 64) * 4
                        + ((size_t)4 * N_LIG + (size_t)2 * N_REC) * 2 * 4;
    const size_t m8_b = (size_t)N_LIG * N_REC;

    int tier;
    if (ws_size >= core_b + kvf32_b + part_b + 2 * m8_b) tier = 0;
    else if (ws_size >= core_b + kvf32_b + part_b) tier = 1;
    else tier = 2;

    char* kv_base = wsb + core_b;
    size_t kv_b = (tier <= 1) ? kvf32_b : kvbf16_b;
    float* kf_l = (float*)kv_base;
    float* vf_l = kf_l + (size_t)N_LIG * 64;
    float* kf_r = vf_l + (size_t)N_LIG * 64;
    float* vf_r = kf_r + (size_t)N_REC * 64;
    bf16* kb_l = (bf16*)kv_base;
    bf16* vb_l = kb_l + (size_t)N_LIG * 64;
    bf16* kb_r = vb_l + (size_t)N_LIG * 64;
    bf16* vb_r = kb_r + (size_t)N_REC * 64;
    float* pO1 = (float*)(kv_base + kv_b);
    float* pO2 = pO1 + (size_t)4 * N_LIG * 64;
    float* pM1 = pO2 + (size_t)2 * N_REC * 64;
    float* pL1 = pM1 + (size_t)4 * N_LIG;
    float* pM2 = pL1 + (size_t)4 * N_LIG;
    float* pL2 = pM2 + (size_t)2 * N_REC;
    unsigned char* m8  = (unsigned char*)(kv_base + kv_b + part_b);
    unsigned char* m8T = m8 + m8_b;

    float* out = (float*)d_out;
    float* x_lig_o = out;
    float* h_lig_o = out + 12288;
    float* x_rec_o = out + 274432;
    float* h_rec_o = out + 299008;

    zero_kernel<<<((int)zero_floats + 255) / 256, 256, 0, stream>>>(aggr_l, (int)zero_floats);

    // k/v projections
    if (tier <= 1) {
        linear64_kernel<float><<<N_LIG, 64, 0, stream>>>(h_lig, k_lig_w, kf_l, 1);
        linear64_kernel<float><<<N_LIG, 64, 0, stream>>>(h_lig, v_lig_w, vf_l, 0);
        linear64_kernel<float><<<N_REC, 64, 0, stream>>>(h_rec, k_rec_w, kf_r, 1);
        linear64_kernel<float><<<N_REC, 64, 0, stream>>>(h_rec, v_rec_w, vf_r, 0);
    } else {
        linear64_kernel<bf16><<<N_LIG, 64, 0, stream>>>(h_lig, k_lig_w, kb_l, 1);
        linear64_kernel<bf16><<<N_LIG, 64, 0, stream>>>(h_lig, v_lig_w, vb_l, 0);
        linear64_kernel<bf16><<<N_REC, 64, 0, stream>>>(h_rec, k_rec_w, kb_r, 1);
        linear64_kernel<bf16><<<N_REC, 64, 0, stream>>>(h_rec, v_rec_w, vb_r, 0);
    }

    // fused edge kernels (LDS-staged weights)
    edge_kernel2<F_LIGc, 64><<<E_LIG / 64, 256, 0, stream>>>(
        coords_lig, h_lig, lig_src, lig_dst, lig_efeat,
        lig_em_w1, lig_em_b1, lig_em_g, lig_em_bt, lig_em_w2, lig_em_b2,
        lig_cm_w1, lig_cm_b1, lig_cm_w2, lig_cm_b2,
        aggr_l, cnt_l, xacc_l);
    edge_kernel2<F_RECc, 64><<<E_REC / 64, 256, 0, stream>>>(
        coords_rec, h_rec, rec_src, rec_dst, rec_efeat,
        rec_em_w1, rec_em_b1, rec_em_g, rec_em_bt, rec_em_w2, rec_em_b2,
        rec_cm_w1, rec_cm_b1, rec_cm_w2, rec_cm_b2,
        aggr_r, cnt_r, xacc_r);

    // attention
    if (tier <= 1) {
        if (tier == 0) {
            dim3 bg(N_REC / 64, N_LIG / 64);
            build_masks<<<bg, 256, 0, stream>>>(mask, m8, m8T, N_LIG, N_REC);
            attn_tiled<0><<<(N_LIG / 64) * 4, 256, 0, stream>>>(
                h_lig, q_lig_w, kf_r, vf_r, m8, mask, 0L, 0L,
                pO1, pM1, pL1, N_LIG, N_REC, 4);
            attn_tiled<0><<<(N_REC / 64) * 2, 256, 0, stream>>>(
                h_rec, q_rec_w, kf_l, vf_l, m8T, mask, 0L, 0L,
                pO2, pM2, pL2, N_REC, N_LIG, 2);
        } else {
            attn_tiled<1><<<(N_LIG / 64) * 4, 256, 0, stream>>>(
                h_lig, q_lig_w, kf_r, vf_r, (const unsigned char*)0, mask, (long)N_REC, 1L,
                pO1, pM1, pL1, N_LIG, N_REC, 4);
            attn_tiled<1><<<(N_REC / 64) * 2, 256, 0, stream>>>(
                h_rec, q_rec_w, kf_l, vf_l, (const unsigned char*)0, mask, 1L, (long)N_REC,
                pO2, pM2, pL2, N_REC, N_LIG, 2);
        }
        attn_merge<<<N_LIG, 64, 0, stream>>>(pO1, pM1, pL1, h_lig_o, N_LIG, 4);
        attn_merge<<<N_REC, 64, 0, stream>>>(pO2, pM2, pL2, h_rec_o, N_REC, 2);
    } else {
        attn_row_kernel<bf16><<<N_LIG, 256, N_REC * sizeof(float), stream>>>(
            h_lig, q_lig_w, kb_r, vb_r, mask, (long)N_REC, 1L, h_lig_o, N_REC);
        attn_row_kernel<bf16><<<N_REC, 256, N_LIG * sizeof(float), stream>>>(
            h_rec, q_rec_w, kb_l, vb_l, mask, 1L, (long)N_REC, h_rec_o, N_LIG);
    }

    // node updates
    node_kernel<<<N_LIG, 64, 0, stream>>>(
        h_lig, aggr_l, cnt_l, h_lig_o, orig_h_lig,
        lig_nm_w1, lig_nm_b1, lig_nm_g, lig_nm_bt, lig_nm_w2, lig_nm_b2, h_lig_o);
    node_kernel<<<N_REC, 64, 0, stream>>>(
        h_rec, aggr_r, cnt_r, h_rec_o, orig_h_rec,
        rec_nm_w1, rec_nm_b1, rec_nm_g, rec_nm_bt, rec_nm_w2, rec_nm_b2, h_rec_o);

    // coordinate outputs
    coord_kernel<<<(N_LIG * 3 + 255) / 256, 256, 0, stream>>>(
        orig_coords_lig, coords_lig, xacc_l, cnt_l, x_lig_o, N_LIG * 3);
    coord_kernel<<<(N_REC * 3 + 255) / 256, 256, 0, stream>>>(
        orig_coords_rec, coords_rec, xacc_r, cnt_r, x_rec_o, N_REC * 3);
}

// Round 7
// 1275.480 us; speedup vs baseline: 5.3776x; 1.3849x over previous
//
#include <hip/hip_runtime.h>
#include <hip/hip_bf16.h>

typedef __hip_bfloat16 bf16;
typedef __attribute__((ext_vector_type(8))) short bfrag8;
typedef __attribute__((ext_vector_type(4))) float f32x4;

#define N_LIG 4096
#define N_REC 8192
#define E_LIG 65536
#define E_REC 262144
#define F_LIGc 15
#define F_RECc 27

__device__ __forceinline__ void stf(float* p, size_t i, float v) { p[i] = v; }
__device__ __forceinline__ void stf(bf16* p, size_t i, float v) { p[i] = __float2bfloat16(v); }
__device__ __forceinline__ float ldkv(const float* p, size_t i) { return p[i]; }
__device__ __forceinline__ float ldkv(const bf16* p, size_t i) { return __bfloat162float(p[i]); }
__device__ __forceinline__ short bfbits(float x) {
    bf16 b = __float2bfloat16(x);
    return *(short*)&b;
}

__constant__ float c_inv_sigma[15] = {
    1.0f, 0.6666666667f, 0.4444444444f, 0.2962962963f, 0.1975308642f,
    0.1316872428f, 0.08779149520f, 0.05852766346f, 0.03901844231f,
    0.02601229487f, 0.01734152992f, 0.01156101994f, 0.007707346628f,
    0.005138231085f, 0.003425487390f};

__device__ __forceinline__ float wave_sum(float v) {
    #pragma unroll
    for (int o = 32; o > 0; o >>= 1) v += __shfl_xor(v, o, 64);
    return v;
}

__global__ void zero_kernel(float* __restrict__ p, int n) {
    int i = blockIdx.x * blockDim.x + threadIdx.x;
    if (i < n) p[i] = 0.f;
}

// ============ MFMA edge kernel: 64 edges/block, 4 waves ============
// X(64xIN) @ W1 -> lrelu -> LN -> @W2 = msg (atomic scatter from frags)
// coef = lrelu(msg @ CW1) . cw2  (lane-reduced, never materialized)
// Weights held as B-fragments in registers; X/LN/msg staged in LDS (bf16).
template <int F, int K1S>
__global__ __launch_bounds__(256) void edge_mfma(
    const float* __restrict__ coords, const float* __restrict__ h,
    const int* __restrict__ src, const int* __restrict__ dst,
    const float* __restrict__ efeat,
    const float* __restrict__ w1, const float* __restrict__ b1,
    const float* __restrict__ g, const float* __restrict__ bt,
    const float* __restrict__ w2, const float* __restrict__ b2,
    const float* __restrict__ cw1, const float* __restrict__ cb1,
    const float* __restrict__ cw2, const float* __restrict__ cb2,
    float* __restrict__ aggr, float* __restrict__ cnt, float* __restrict__ xacc)
{
    constexpr int IN = 143 + F;          // 128 + F + 15
    constexpr int KP = K1S * 32 + 8;     // padded X row stride (bf16)
    __shared__ __align__(16) unsigned short xb[64 * KP];
    __shared__ __align__(16) float h1f[64 * 68];          // reused as msgb after LN
    __shared__ __align__(16) unsigned short h1b[64 * 72];
    __shared__ float sums[256], sums2[256];
    __shared__ float stat_m[64], stat_r[64];
    __shared__ float coefp[4][64];
    __shared__ int dsts[64];
    __shared__ float xr_s[64][3], d2s[64];
    unsigned short* msgb = (unsigned short*)h1f;          // alias (9216 <= 17408)

    const int t  = threadIdx.x;
    const int wv = t >> 6;
    const int L  = t & 63;
    const int lm = L & 15;
    const int qd = L >> 4;
    const int e0 = blockIdx.x * 64;
    const int n  = wv * 16 + lm;         // output channel this lane owns in GEMMs

    // ---- weight B-fragments (registers, once per block) ----
    bfrag8 w1f[K1S], w2f[2], c1f[2];
    #pragma unroll
    for (int kk = 0; kk < K1S; ++kk)
        #pragma unroll
        for (int j = 0; j < 8; ++j) {
            int k = kk * 32 + qd * 8 + j;
            w1f[kk][j] = (k < IN) ? bfbits(w1[k * 64 + n]) : (short)0;
        }
    #pragma unroll
    for (int kk = 0; kk < 2; ++kk)
        #pragma unroll
        for (int j = 0; j < 8; ++j) {
            int k = kk * 32 + qd * 8 + j;
            w2f[kk][j] = bfbits(w2[k * 64 + n]);
            c1f[kk][j] = bfbits(cw1[k * 64 + n]);
        }
    const float b1n = b1[n], b2n = b2[n], cb1n = cb1[n], cw2n = cw2[n];

    // ---- per-edge scalars ----
    if (t < 64) {
        int e = e0 + t;
        int s = src[e], d = dst[e];
        dsts[t] = d;
        float x0 = coords[s * 3 + 0] - coords[d * 3 + 0];
        float x1 = coords[s * 3 + 1] - coords[d * 3 + 1];
        float x2 = coords[s * 3 + 2] - coords[d * 3 + 2];
        xr_s[t][0] = x0; xr_s[t][1] = x1; xr_s[t][2] = x2;
        d2s[t] = x0 * x0 + x1 * x1 + x2 * x2;
    }

    // ---- stage X: [h_src | h_dst | efeat | rbf | 0-pad] as bf16 ----
    for (int p = 0; p < 16; ++p) {
        int e = (t >> 6) + 4 * p;        // wave-uniform edge
        int ge = e0 + e;
        int s = src[ge], d = dst[ge];
        int j = t & 63;
        xb[e * KP + j]      = bfbits(h[(size_t)s * 64 + j]);
        xb[e * KP + 64 + j] = bfbits(h[(size_t)d * 64 + j]);
    }
    for (int idx = t; idx < 64 * F; idx += 256) {
        int e = idx / F, f = idx - e * F;
        xb[e * KP + 128 + f] = bfbits(efeat[(size_t)(e0 + e) * F + f]);
    }
    {
        constexpr int PER = K1S * 32 - IN;
        for (int idx = t; idx < 64 * PER; idx += 256) {
            int e = idx / PER, k = idx - e * PER;
            xb[e * KP + IN + k] = 0;
        }
    }
    __syncthreads();
    for (int idx = t; idx < 64 * 15; idx += 256) {
        int e = idx / 15, s5 = idx - e * 15;
        xb[e * KP + 128 + F + s5] = bfbits(__expf(-d2s[e] * c_inv_sigma[s5]));
    }
    __syncthreads();

    // ---- GEMM 1: H1 = lrelu(X @ W1 + b1) -> h1f ----
    #pragma unroll
    for (int m = 0; m < 4; ++m) {
        f32x4 acc = {0.f, 0.f, 0.f, 0.f};
        #pragma unroll
        for (int kk = 0; kk < K1S; ++kk) {
            bfrag8 a = *(const bfrag8*)&xb[(m * 16 + lm) * KP + kk * 32 + qd * 8];
            acc = __builtin_amdgcn_mfma_f32_16x16x32_bf16(a, w1f[kk], acc, 0, 0, 0);
        }
        #pragma unroll
        for (int r = 0; r < 4; ++r) {
            int mr = m * 16 + qd * 4 + r;
            float v = acc[r] + b1n;
            v = v > 0.f ? v : 0.01f * v;
            h1f[mr * 68 + n] = v;
        }
    }
    __syncthreads();

    // ---- LayerNorm over 64 channels per edge ----
    {
        int e = t >> 2, seg = (t & 3) * 16;
        float s1 = 0.f, s2 = 0.f;
        #pragma unroll
        for (int j = 0; j < 16; ++j) {
            float v = h1f[e * 68 + seg + j];
            s1 += v; s2 += v * v;
        }
        sums[t] = s1; sums2[t] = s2;
    }
    __syncthreads();
    if (t < 64) {
        float s1 = sums[4 * t] + sums[4 * t + 1] + sums[4 * t + 2] + sums[4 * t + 3];
        float s2 = sums2[4 * t] + sums2[4 * t + 1] + sums2[4 * t + 2] + sums2[4 * t + 3];
        float mean = s1 * (1.f / 64.f);
        float var = s2 * (1.f / 64.f) - mean * mean;
        stat_m[t] = mean;
        stat_r[t] = rsqrtf(fmaxf(var, 0.f) + 1e-5f);
    }
    __syncthreads();
    for (int idx = t; idx < 4096; idx += 256) {
        int e = idx >> 6, j = idx & 63;
        float v = (h1f[e * 68 + j] - stat_m[e]) * stat_r[e] * g[j] + bt[j];
        h1b[e * 72 + j] = bfbits(v);
    }
    __syncthreads();   // h1b ready; h1f dead -> msgb may overwrite it

    // ---- GEMM 2: msg = H1n @ W2 + b2 ; atomic scatter + msgb ----
    #pragma unroll
    for (int m = 0; m < 4; ++m) {
        f32x4 acc = {0.f, 0.f, 0.f, 0.f};
        #pragma unroll
        for (int kk = 0; kk < 2; ++kk) {
            bfrag8 a = *(const bfrag8*)&h1b[(m * 16 + lm) * 72 + kk * 32 + qd * 8];
            acc = __builtin_amdgcn_mfma_f32_16x16x32_bf16(a, w2f[kk], acc, 0, 0, 0);
        }
        #pragma unroll
        for (int r = 0; r < 4; ++r) {
            int mr = m * 16 + qd * 4 + r;
            float v = acc[r] + b2n;
            atomicAdd(&aggr[(size_t)dsts[mr] * 64 + n], v);
            msgb[mr * 72 + n] = bfbits(v);
        }
    }
    __syncthreads();

    // ---- GEMM 3: T = lrelu(msg @ CW1 + cb1); coef = T . cw2 (lane-reduced) ----
    #pragma unroll
    for (int m = 0; m < 4; ++m) {
        f32x4 acc = {0.f, 0.f, 0.f, 0.f};
        #pragma unroll
        for (int kk = 0; kk < 2; ++kk) {
            bfrag8 a = *(const bfrag8*)&msgb[(m * 16 + lm) * 72 + kk * 32 + qd * 8];
            acc = __builtin_amdgcn_mfma_f32_16x16x32_bf16(a, c1f[kk], acc, 0, 0, 0);
        }
        #pragma unroll
        for (int r = 0; r < 4; ++r) {
            float v = acc[r] + cb1n;
            v = v > 0.f ? v : 0.01f * v;
            v *= cw2n;
            v += __shfl_xor(v, 1);
            v += __shfl_xor(v, 2);
            v += __shfl_xor(v, 4);
            v += __shfl_xor(v, 8);
            if (lm == 0) coefp[wv][m * 16 + qd * 4 + r] = v;
        }
    }
    __syncthreads();
    if (t < 64) {
        float coef = coefp[0][t] + coefp[1][t] + coefp[2][t] + coefp[3][t] + cb2[0];
        int d = dsts[t];
        atomicAdd(&cnt[d], 1.f);
        atomicAdd(&xacc[d * 3 + 0], xr_s[t][0] * coef);
        atomicAdd(&xacc[d * 3 + 1], xr_s[t][1] * coef);
        atomicAdd(&xacc[d * 3 + 2], xr_s[t][2] * coef);
    }
}

// ---------------- k/v projection ----------------
template <typename OT>
__global__ __launch_bounds__(64) void linear64_kernel(
    const float* __restrict__ h, const float* __restrict__ w,
    OT* __restrict__ out, int do_lrelu)
{
    int node = blockIdx.x;
    int j = threadIdx.x;
    __shared__ float x[64];
    x[j] = h[(size_t)node * 64 + j];
    __syncthreads();
    float acc = 0.f;
    #pragma unroll 8
    for (int i = 0; i < 64; ++i) acc += x[i] * w[i * 64 + j];
    if (do_lrelu) acc = acc > 0.f ? acc : 0.01f * acc;
    stf(out, (size_t)node * 64 + j, acc);
}

// ---------------- u8 mask build: m8[r][c], m8T[c][r] ----------------
__global__ __launch_bounds__(256) void build_masks(
    const float* __restrict__ mask, unsigned char* __restrict__ m8,
    unsigned char* __restrict__ m8T, int R, int C)
{
    __shared__ __align__(16) unsigned char tl[64 * 80];
    int r0 = blockIdx.y * 64, c0 = blockIdx.x * 64;
    int t = threadIdx.x;
    int cs = (t & 15) * 4;
    #pragma unroll
    for (int rr = 0; rr < 4; ++rr) {
        int r = (t >> 4) + rr * 16;
        unsigned b0 = (mask[(size_t)(r0 + r) * C + c0 + cs + 0] != 0.f);
        unsigned b1 = (mask[(size_t)(r0 + r) * C + c0 + cs + 1] != 0.f);
        unsigned b2 = (mask[(size_t)(r0 + r) * C + c0 + cs + 2] != 0.f);
        unsigned b3 = (mask[(size_t)(r0 + r) * C + c0 + cs + 3] != 0.f);
        *(unsigned*)&m8[(size_t)(r0 + r) * C + c0 + cs] = b0 | (b1 << 8) | (b2 << 16) | (b3 << 24);
        tl[(cs + 0) * 80 + r] = (unsigned char)b0;
        tl[(cs + 1) * 80 + r] = (unsigned char)b1;
        tl[(cs + 2) * 80 + r] = (unsigned char)b2;
        tl[(cs + 3) * 80 + r] = (unsigned char)b3;
    }
    __syncthreads();
    {
        int c = t >> 2, rs = (t & 3) * 16;
        *(uint4*)&m8T[(size_t)(c0 + c) * R + r0 + rs] = *(const uint4*)&tl[c * 80 + rs];
    }
}

// ---------------- tiled masked flash attention with column splits ----------------
template <int MMODE>  // 0: u8 mask, 1: strided f32 mask
__global__ __launch_bounds__(256) void attn_tiled(
    const float* __restrict__ h, const float* __restrict__ qw,
    const float* __restrict__ kk, const float* __restrict__ vv,
    const unsigned char* __restrict__ m8,
    const float* __restrict__ maskf, long mrs, long mcs,
    float* __restrict__ pO, float* __restrict__ pM, float* __restrict__ pL,
    int n_rows, int n_cols, int nsplit)
{
    const int t = threadIdx.x;
    const int rb = blockIdx.x / nsplit;
    const int sp = blockIdx.x - rb * nsplit;
    const int r0 = rb * 64;
    const int cols_per = n_cols / nsplit;
    const int c_begin = sp * cols_per;

    __shared__ __align__(16) float q_s[64 * 68];
    __shared__ __align__(16) float ktv[64 * 68];
    __shared__ __align__(16) float p_s[64 * 68];
    __shared__ float mrow[64], lrow[64], anew[64], mnew[64];
    __shared__ float lpart[256];
    __shared__ __align__(16) unsigned char mt[4096];

    const int cg = t & 31;
    const int rg = (t >> 5) * 8;

    for (int u = 0; u < 16; ++u) {
        int i = t + 256 * u;
        int r = i >> 6, d = i & 63;
        p_s[r * 68 + d] = h[(size_t)(r0 + r) * 64 + d];
        ktv[d * 68 + r] = qw[(size_t)r * 64 + d];
    }
    __syncthreads();
    {
        float a0[8], a1[8];
        #pragma unroll
        for (int x = 0; x < 8; ++x) { a0[x] = 0.f; a1[x] = 0.f; }
        for (int d = 0; d < 64; d += 4) {
            float4 b0 = *(const float4*)&ktv[cg * 68 + d];
            float4 b1 = *(const float4*)&ktv[(cg + 32) * 68 + d];
            #pragma unroll
            for (int x = 0; x < 8; ++x) {
                float4 a = *(const float4*)&p_s[(rg + x) * 68 + d];
                a0[x] += a.x * b0.x + a.y * b0.y + a.z * b0.z + a.w * b0.w;
                a1[x] += a.x * b1.x + a.y * b1.y + a.z * b1.z + a.w * b1.w;
            }
        }
        __syncthreads();
        #pragma unroll
        for (int x = 0; x < 8; ++x) {
            float v0 = a0[x]; v0 = v0 > 0.f ? v0 : 0.01f * v0;
            float v1 = a1[x]; v1 = v1 > 0.f ? v1 : 0.01f * v1;
            q_s[(rg + x) * 68 + cg] = v0;
            q_s[(rg + x) * 68 + cg + 32] = v1;
        }
    }
    if (t < 64) { mrow[t] = -1e30f; lrow[t] = 0.f; }
    float o0[8], o1[8];
    #pragma unroll
    for (int x = 0; x < 8; ++x) { o0[x] = 0.f; o1[x] = 0.f; }
    __syncthreads();

    for (int c0 = c_begin; c0 < c_begin + cols_per; c0 += 64) {
        #pragma unroll
        for (int u = 0; u < 4; ++u) {
            int i4 = (t + 256 * u) * 4;
            int c = i4 >> 6, d = i4 & 63;
            *(float4*)&ktv[c * 68 + d] = *(const float4*)&kk[(size_t)(c0 + c) * 64 + d];
        }
        if (MMODE == 0) {
            int r = t >> 2, seg = (t & 3) * 16;
            *(uint4*)&mt[r * 64 + seg] =
                *(const uint4*)&m8[(size_t)(r0 + r) * n_cols + c0 + seg];
        } else {
            #pragma unroll
            for (int u = 0; u < 16; ++u) {
                int i = t + 256 * u;
                int r = i >> 6, c = i & 63;
                mt[r * 64 + c] = (unsigned char)(
                    maskf[(size_t)(r0 + r) * mrs + (size_t)(c0 + c) * mcs] != 0.f);
            }
        }
        __syncthreads();

        {
            float s0[8], s1[8];
            #pragma unroll
            for (int x = 0; x < 8; ++x) { s0[x] = 0.f; s1[x] = 0.f; }
            for (int d = 0; d < 64; d += 4) {
                float4 b0 = *(const float4*)&ktv[cg * 68 + d];
                float4 b1 = *(const float4*)&ktv[(cg + 32) * 68 + d];
                #pragma unroll
                for (int x = 0; x < 8; ++x) {
                    float4 a = *(const float4*)&q_s[(rg + x) * 68 + d];
                    s0[x] += a.x * b0.x + a.y * b0.y + a.z * b0.z + a.w * b0.w;
                    s1[x] += a.x * b1.x + a.y * b1.y + a.z * b1.z + a.w * b1.w;
                }
            }
            #pragma unroll
            for (int x = 0; x < 8; ++x) {
                int r = rg + x;
                p_s[r * 68 + cg]      = mt[r * 64 + cg]      ? s0[x] : -1000.f;
                p_s[r * 68 + cg + 32] = mt[r * 64 + cg + 32] ? s1[x] : -1000.f;
            }
        }
        __syncthreads();

        #pragma unroll
        for (int u = 0; u < 4; ++u) {
            int i4 = (t + 256 * u) * 4;
            int c = i4 >> 6, d = i4 & 63;
            float4 v4 = *(const float4*)&vv[(size_t)(c0 + c) * 64 + d];
            ktv[(d + 0) * 68 + c] = v4.x;
            ktv[(d + 1) * 68 + c] = v4.y;
            ktv[(d + 2) * 68 + c] = v4.z;
            ktv[(d + 3) * 68 + c] = v4.w;
        }
        if (t < 64) {
            float mx = -1e30f;
            for (int c = 0; c < 64; c += 4) {
                float4 s4 = *(const float4*)&p_s[t * 68 + c];
                mx = fmaxf(mx, fmaxf(fmaxf(s4.x, s4.y), fmaxf(s4.z, s4.w)));
            }
            float mn = fmaxf(mrow[t], mx);
            mnew[t] = mn;
            anew[t] = __expf(mrow[t] - mn);
            mrow[t] = mn;
        }
        __syncthreads();

        {
            int r = t >> 2, seg = (t & 3) * 16;
            float mr = mnew[r];
            float ps = 0.f;
            #pragma unroll
            for (int c = seg; c < seg + 16; c += 4) {
                float4 s4 = *(float4*)&p_s[r * 68 + c];
                s4.x = __expf(s4.x - mr);
                s4.y = __expf(s4.y - mr);
                s4.z = __expf(s4.z - mr);
                s4.w = __expf(s4.w - mr);
                ps += s4.x + s4.y + s4.z + s4.w;
                *(float4*)&p_s[r * 68 + c] = s4;
            }
            lpart[t] = ps;
        }
        __syncthreads();
        if (t < 64)
            lrow[t] = lrow[t] * anew[t] +
                      lpart[t * 4] + lpart[t * 4 + 1] + lpart[t * 4 + 2] + lpart[t * 4 + 3];

        {
            #pragma unroll
            for (int x = 0; x < 8; ++x) {
                float a = anew[rg + x];
                o0[x] *= a;
                o1[x] *= a;
            }
            for (int c = 0; c < 64; c += 4) {
                float4 b0 = *(const float4*)&ktv[cg * 68 + c];
                float4 b1 = *(const float4*)&ktv[(cg + 32) * 68 + c];
                #pragma unroll
                for (int x = 0; x < 8; ++x) {
                    float4 p = *(const float4*)&p_s[(rg + x) * 68 + c];
                    o0[x] += p.x * b0.x + p.y * b0.y + p.z * b0.z + p.w * b0.w;
                    o1[x] += p.x * b1.x + p.y * b1.y + p.z * b1.z + p.w * b1.w;
                }
            }
        }
        __syncthreads();
    }

    #pragma unroll
    for (int x = 0; x < 8; ++x) {
        size_t base = ((size_t)sp * n_rows + r0 + rg + x) * 64;
        pO[base + cg] = o0[x];
        pO[base + cg + 32] = o1[x];
    }
    if (t < 64) {
        pM[(size_t)sp * n_rows + r0 + t] = mrow[t];
        pL[(size_t)sp * n_rows + r0 + t] = lrow[t];
    }
}

// ---------------- merge split partials ----------------
__global__ __launch_bounds__(64) void attn_merge(
    const float* __restrict__ pO, const float* __restrict__ pM, const float* __restrict__ pL,
    float* __restrict__ out, int n_rows, int nsplit)
{
    int r = blockIdx.x;
    int d = threadIdx.x;
    float mstar = -1e30f;
    for (int s = 0; s < nsplit; ++s) mstar = fmaxf(mstar, pM[(size_t)s * n_rows + r]);
    float L = 0.f, O = 0.f;
    for (int s = 0; s < nsplit; ++s) {
        float w = __expf(pM[(size_t)s * n_rows + r] - mstar);
        L += pL[(size_t)s * n_rows + r] * w;
        O += pO[((size_t)s * n_rows + r) * 64 + d] * w;
    }
    out[(size_t)r * 64 + d] = O / L;
}

// ---------------- per-row attention (tier-2 fallback) ----------------
template <typename KT>
__global__ __launch_bounds__(256) void attn_row_kernel(
    const float* __restrict__ h, const float* __restrict__ qw,
    const KT* __restrict__ k, const KT* __restrict__ v,
    const float* __restrict__ mask, long mrs, long mcs,
    float* __restrict__ out, int n_cols)
{
    int row = blockIdx.x;
    int tid = threadIdx.x;
    extern __shared__ float sc[];
    __shared__ float hrow[64];
    __shared__ float qrow[64];
    __shared__ float red[4];
    __shared__ float opart[4][64];

    if (tid < 64) hrow[tid] = h[(size_t)row * 64 + tid];
    __syncthreads();
    if (tid < 64) {
        float a = 0.f;
        #pragma unroll 8
        for (int i = 0; i < 64; ++i) a += hrow[i] * qw[i * 64 + tid];
        qrow[tid] = a > 0.f ? a : 0.01f * a;
    }
    __syncthreads();

    float lmax = -1e30f;
    for (int c = tid; c < n_cols; c += 256) {
        const KT* kr = k + (size_t)c * 64;
        float s = 0.f;
        #pragma unroll 8
        for (int i = 0; i < 64; ++i) s += qrow[i] * ldkv(kr, i);
        float m = mask[(size_t)row * mrs + (size_t)c * mcs];
        s = m * s - 1000.f * (1.f - m);
        sc[c] = s;
        lmax = fmaxf(lmax, s);
    }
    #pragma unroll
    for (int o = 32; o > 0; o >>= 1) lmax = fmaxf(lmax, __shfl_xor(lmax, o, 64));
    int wid = tid >> 6;
    if ((tid & 63) == 0) red[wid] = lmax;
    __syncthreads();
    float bmax = fmaxf(fmaxf(red[0], red[1]), fmaxf(red[2], red[3]));
    __syncthreads();

    float lsum = 0.f;
    for (int c = tid; c < n_cols; c += 256) {
        float e = __expf(sc[c] - bmax);
        sc[c] = e;
        lsum += e;
    }
    lsum = wave_sum(lsum);
    if ((tid & 63) == 0) red[wid] = lsum;
    __syncthreads();
    float inv = 1.f / (red[0] + red[1] + red[2] + red[3]);

    int dd = tid & 63;
    float o = 0.f;
    for (int c = wid; c < n_cols; c += 4) o += sc[c] * ldkv(v, (size_t)c * 64 + dd);
    opart[wid][dd] = o;
    __syncthreads();
    if (wid == 0)
        out[(size_t)row * 64 + dd] =
            (opart[0][dd] + opart[1][dd] + opart[2][dd] + opart[3][dd]) * inv;
}

// ---------------- node feature update ----------------
__global__ __launch_bounds__(64) void node_kernel(
    const float* __restrict__ h, const float* __restrict__ aggr,
    const float* __restrict__ cnt, const float* att,  // aliases h_out
    const float* __restrict__ orig_h,
    const float* __restrict__ w1, const float* __restrict__ b1,
    const float* __restrict__ g, const float* __restrict__ bt,
    const float* __restrict__ w2, const float* __restrict__ b2,
    float* h_out)
{
    int node = blockIdx.x;
    int j = threadIdx.x;
    __shared__ float xin[256];
    __shared__ float hbuf[64];
    float invc = 1.f / fmaxf(cnt[node], 1.f);
    float hv = h[(size_t)node * 64 + j];
    xin[j]       = hv;
    xin[64 + j]  = aggr[(size_t)node * 64 + j] * invc;
    xin[128 + j] = att[(size_t)node * 64 + j];
    xin[192 + j] = orig_h[(size_t)node * 64 + j];
    __syncthreads();
    float acc = b1[j];
    #pragma unroll 4
    for (int i = 0; i < 256; ++i) acc += xin[i] * w1[i * 64 + j];
    acc = acc > 0.f ? acc : 0.01f * acc;
    float mean = wave_sum(acc) * (1.f / 64.f);
    float cv = acc - mean;
    float var = wave_sum(cv * cv) * (1.f / 64.f);
    float y = cv * rsqrtf(var + 1e-5f) * g[j] + bt[j];
    hbuf[j] = y;
    __syncthreads();
    float o = b2[j];
    #pragma unroll 8
    for (int i = 0; i < 64; ++i) o += hbuf[i] * w2[i * 64 + j];
    h_out[(size_t)node * 64 + j] = 0.5f * o + 0.5f * hv;
}

// ---------------- coordinate output ----------------
__global__ void coord_kernel(
    const float* __restrict__ orig, const float* __restrict__ coords,
    const float* __restrict__ xacc, const float* __restrict__ cnt,
    float* __restrict__ out, int n3)
{
    int i = blockIdx.x * blockDim.x + threadIdx.x;
    if (i >= n3) return;
    int node = i / 3;
    float invc = 1.f / fmaxf(cnt[node], 1.f);
    out[i] = 0.25f * orig[i] + 0.75f * coords[i] + xacc[i] * invc;
}

extern "C" void kernel_launch(void* const* d_in, const int* in_sizes, int n_in,
                              void* d_out, int out_size, void* d_ws, size_t ws_size,
                              hipStream_t stream)
{
    const float* coords_lig      = (const float*)d_in[0];
    const float* h_lig           = (const float*)d_in[1];
    const float* orig_h_lig      = (const float*)d_in[2];
    const float* orig_coords_lig = (const float*)d_in[3];
    const float* coords_rec      = (const float*)d_in[4];
    const float* h_rec           = (const float*)d_in[5];
    const float* orig_h_rec      = (const float*)d_in[6];
    const float* orig_coords_rec = (const float*)d_in[7];
    const int* lig_src   = (const int*)d_in[8];
    const int* lig_dst   = (const int*)d_in[9];
    const float* lig_efeat = (const float*)d_in[10];
    const int* rec_src   = (const int*)d_in[11];
    const int* rec_dst   = (const int*)d_in[12];
    const float* rec_efeat = (const float*)d_in[13];
    const float* mask      = (const float*)d_in[14];
    const float *lig_em_w1 = (const float*)d_in[15], *lig_em_b1 = (const float*)d_in[16];
    const float *lig_em_g  = (const float*)d_in[17], *lig_em_bt = (const float*)d_in[18];
    const float *lig_em_w2 = (const float*)d_in[19], *lig_em_b2 = (const float*)d_in[20];
    const float *rec_em_w1 = (const float*)d_in[21], *rec_em_b1 = (const float*)d_in[22];
    const float *rec_em_g  = (const float*)d_in[23], *rec_em_bt = (const float*)d_in[24];
    const float *rec_em_w2 = (const float*)d_in[25], *rec_em_b2 = (const float*)d_in[26];
    const float *lig_cm_w1 = (const float*)d_in[27], *lig_cm_b1 = (const float*)d_in[28];
    const float *lig_cm_w2 = (const float*)d_in[29], *lig_cm_b2 = (const float*)d_in[30];
    const float *rec_cm_w1 = (const float*)d_in[31], *rec_cm_b1 = (const float*)d_in[32];
    const float *rec_cm_w2 = (const float*)d_in[33], *rec_cm_b2 = (const float*)d_in[34];
    const float *q_lig_w = (const float*)d_in[35], *k_lig_w = (const float*)d_in[36];
    const float *v_lig_w = (const float*)d_in[37], *q_rec_w = (const float*)d_in[38];
    const float *k_rec_w = (const float*)d_in[39], *v_rec_w = (const float*)d_in[40];
    const float *lig_nm_w1 = (const float*)d_in[41], *lig_nm_b1 = (const float*)d_in[42];
    const float *lig_nm_g  = (const float*)d_in[43], *lig_nm_bt = (const float*)d_in[44];
    const float *lig_nm_w2 = (const float*)d_in[45], *lig_nm_b2 = (const float*)d_in[46];
    const float *rec_nm_w1 = (const float*)d_in[47], *rec_nm_b1 = (const float*)d_in[48];
    const float *rec_nm_g  = (const float*)d_in[49], *rec_nm_bt = (const float*)d_in[50];
    const float *rec_nm_w2 = (const float*)d_in[51], *rec_nm_b2 = (const float*)d_in[52];

    char* wsb = (char*)d_ws;
    float* aggr_l = (float*)(wsb + 16);
    float* aggr_r = aggr_l + (size_t)N_LIG * 64;
    float* cnt_l  = aggr_r + (size_t)N_REC * 64;
    float* cnt_r  = cnt_l + N_LIG;
    float* xacc_l = cnt_r + N_REC;
    float* xacc_r = xacc_l + (size_t)N_LIG * 3;
    const size_t zero_floats =
        (size_t)N_LIG * 64 + (size_t)N_REC * 64 + N_LIG + N_REC + N_LIG * 3 + N_REC * 3;
    const size_t core_b = 16 + zero_floats * 4;
    const size_t kvf32_b  = (size_t)(N_LIG + N_REC) * 64 * 2 * 4;
    const size_t kvbf16_b = kvf32_b / 2;
    const size_t part_b = ((size_t)4 * N_LIG * 64 + (size_t)2 * N_REC * 64) * 4
                        + ((size_t)4 * N_LIG + (size_t)2 * N_REC) * 2 * 4;
    const size_t m8_b = (size_t)N_LIG * N_REC;

    int tier;
    if (ws_size >= core_b + kvf32_b + part_b + 2 * m8_b) tier = 0;
    else if (ws_size >= core_b + kvf32_b + part_b) tier = 1;
    else tier = 2;

    char* kv_base = wsb + core_b;
    size_t kv_b = (tier <= 1) ? kvf32_b : kvbf16_b;
    float* kf_l = (float*)kv_base;
    float* vf_l = kf_l + (size_t)N_LIG * 64;
    float* kf_r = vf_l + (size_t)N_LIG * 64;
    float* vf_r = kf_r + (size_t)N_REC * 64;
    bf16* kb_l = (bf16*)kv_base;
    bf16* vb_l = kb_l + (size_t)N_LIG * 64;
    bf16* kb_r = vb_l + (size_t)N_LIG * 64;
    bf16* vb_r = kb_r + (size_t)N_REC * 64;
    float* pO1 = (float*)(kv_base + kv_b);
    float* pO2 = pO1 + (size_t)4 * N_LIG * 64;
    float* pM1 = pO2 + (size_t)2 * N_REC * 64;
    float* pL1 = pM1 + (size_t)4 * N_LIG;
    float* pM2 = pL1 + (size_t)4 * N_LIG;
    float* pL2 = pM2 + (size_t)2 * N_REC;
    unsigned char* m8  = (unsigned char*)(kv_base + kv_b + part_b);
    unsigned char* m8T = m8 + m8_b;

    float* out = (float*)d_out;
    float* x_lig_o = out;
    float* h_lig_o = out + 12288;
    float* x_rec_o = out + 274432;
    float* h_rec_o = out + 299008;

    zero_kernel<<<((int)zero_floats + 255) / 256, 256, 0, stream>>>(aggr_l, (int)zero_floats);

    // k/v projections
    if (tier <= 1) {
        linear64_kernel<float><<<N_LIG, 64, 0, stream>>>(h_lig, k_lig_w, kf_l, 1);
        linear64_kernel<float><<<N_LIG, 64, 0, stream>>>(h_lig, v_lig_w, vf_l, 0);
        linear64_kernel<float><<<N_REC, 64, 0, stream>>>(h_rec, k_rec_w, kf_r, 1);
        linear64_kernel<float><<<N_REC, 64, 0, stream>>>(h_rec, v_rec_w, vf_r, 0);
    } else {
        linear64_kernel<bf16><<<N_LIG, 64, 0, stream>>>(h_lig, k_lig_w, kb_l, 1);
        linear64_kernel<bf16><<<N_LIG, 64, 0, stream>>>(h_lig, v_lig_w, vb_l, 0);
        linear64_kernel<bf16><<<N_REC, 64, 0, stream>>>(h_rec, k_rec_w, kb_r, 1);
        linear64_kernel<bf16><<<N_REC, 64, 0, stream>>>(h_rec, v_rec_w, vb_r, 0);
    }

    // MFMA edge kernels
    edge_mfma<F_LIGc, 5><<<E_LIG / 64, 256, 0, stream>>>(
        coords_lig, h_lig, lig_src, lig_dst, lig_efeat,
        lig_em_w1, lig_em_b1, lig_em_g, lig_em_bt, lig_em_w2, lig_em_b2,
        lig_cm_w1, lig_cm_b1, lig_cm_w2, lig_cm_b2,
        aggr_l, cnt_l, xacc_l);
    edge_mfma<F_RECc, 6><<<E_REC / 64, 256, 0, stream>>>(
        coords_rec, h_rec, rec_src, rec_dst, rec_efeat,
        rec_em_w1, rec_em_b1, rec_em_g, rec_em_bt, rec_em_w2, rec_em_b2,
        rec_cm_w1, rec_cm_b1, rec_cm_w2, rec_cm_b2,
        aggr_r, cnt_r, xacc_r);

    // attention
    if (tier <= 1) {
        if (tier == 0) {
            dim3 bg(N_REC / 64, N_LIG / 64);
            build_masks<<<bg, 256, 0, stream>>>(mask, m8, m8T, N_LIG, N_REC);
            attn_tiled<0><<<(N_LIG / 64) * 4, 256, 0, stream>>>(
                h_lig, q_lig_w, kf_r, vf_r, m8, mask, 0L, 0L,
                pO1, pM1, pL1, N_LIG, N_REC, 4);
            attn_tiled<0><<<(N_REC / 64) * 2, 256, 0, stream>>>(
                h_rec, q_rec_w, kf_l, vf_l, m8T, mask, 0L, 0L,
                pO2, pM2, pL2, N_REC, N_LIG, 2);
        } else {
            attn_tiled<1><<<(N_LIG / 64) * 4, 256, 0, stream>>>(
                h_lig, q_lig_w, kf_r, vf_r, (const unsigned char*)0, mask, (long)N_REC, 1L,
                pO1, pM1, pL1, N_LIG, N_REC, 4);
            attn_tiled<1><<<(N_REC / 64) * 2, 256, 0, stream>>>(
                h_rec, q_rec_w, kf_l, vf_l, (const unsigned char*)0, mask, 1L, (long)N_REC,
                pO2, pM2, pL2, N_REC, N_LIG, 2);
        }
        attn_merge<<<N_LIG, 64, 0, stream>>>(pO1, pM1, pL1, h_lig_o, N_LIG, 4);
        attn_merge<<<N_REC, 64, 0, stream>>>(pO2, pM2, pL2, h_rec_o, N_REC, 2);
    } else {
        attn_row_kernel<bf16><<<N_LIG, 256, N_REC * sizeof(float), stream>>>(
            h_lig, q_lig_w, kb_r, vb_r, mask, (long)N_REC, 1L, h_lig_o, N_REC);
        attn_row_kernel<bf16><<<N_REC, 256, N_LIG * sizeof(float), stream>>>(
            h_rec, q_rec_w, kb_l, vb_l, mask, 1L, (long)N_REC, h_rec_o, N_LIG);
    }

    // node updates
    node_kernel<<<N_LIG, 64, 0, stream>>>(
        h_lig, aggr_l, cnt_l, h_lig_o, orig_h_lig,
        lig_nm_w1, lig_nm_b1, lig_nm_g, lig_nm_bt, lig_nm_w2, lig_nm_b2, h_lig_o);
    node_kernel<<<N_REC, 64, 0, stream>>>(
        h_rec, aggr_r, cnt_r, h_rec_o, orig_h_rec,
        rec_nm_w1, rec_nm_b1, rec_nm_g, rec_nm_bt, rec_nm_w2, rec_nm_b2, h_rec_o);

    // coordinate outputs
    coord_kernel<<<(N_LIG * 3 + 255) / 256, 256, 0, stream>>>(
        orig_coords_lig, coords_lig, xacc_l, cnt_l, x_lig_o, N_LIG * 3);
    coord_kernel<<<(N_REC * 3 + 255) / 256, 256, 0, stream>>>(
        orig_coords_rec, coords_rec, xacc_r, cnt_r, x_rec_o, N_REC * 3);
}

// Round 8
// 803.128 us; speedup vs baseline: 8.5404x; 1.5881x over previous
//
#include <hip/hip_runtime.h>
#include <hip/hip_bf16.h>

typedef __hip_bfloat16 bf16;
typedef __attribute__((ext_vector_type(8))) short bfrag8;
typedef __attribute__((ext_vector_type(4))) float f32x4;

#define N_LIG 4096
#define N_REC 8192
#define E_LIG 65536
#define E_REC 262144
#define F_LIGc 15
#define F_RECc 27

__device__ __forceinline__ float ldkv(const float* p, size_t i) { return p[i]; }
__device__ __forceinline__ float ldkv(const bf16* p, size_t i) { return __bfloat162float(p[i]); }
__device__ __forceinline__ short bfbits(float x) {
    bf16 b = __float2bfloat16(x);
    return *(short*)&b;
}

__constant__ float c_inv_sigma[15] = {
    1.0f, 0.6666666667f, 0.4444444444f, 0.2962962963f, 0.1975308642f,
    0.1316872428f, 0.08779149520f, 0.05852766346f, 0.03901844231f,
    0.02601229487f, 0.01734152992f, 0.01156101994f, 0.007707346628f,
    0.005138231085f, 0.003425487390f};

__device__ __forceinline__ float wave_sum(float v) {
    #pragma unroll
    for (int o = 32; o > 0; o >>= 1) v += __shfl_xor(v, o, 64);
    return v;
}
__device__ __forceinline__ float quad_max(float v) {
    v = fmaxf(v, __shfl_xor(v, 1)); v = fmaxf(v, __shfl_xor(v, 2));
    v = fmaxf(v, __shfl_xor(v, 4)); v = fmaxf(v, __shfl_xor(v, 8));
    return v;
}
__device__ __forceinline__ float quad_sum(float v) {
    v += __shfl_xor(v, 1); v += __shfl_xor(v, 2);
    v += __shfl_xor(v, 4); v += __shfl_xor(v, 8);
    return v;
}

__global__ void zero_kernel(float* __restrict__ p, int n) {
    int i = blockIdx.x * blockDim.x + threadIdx.x;
    if (i < n) p[i] = 0.f;
}

// ============ MFMA edge kernel (unchanged from R7 — verified) ============
template <int F, int K1S>
__global__ __launch_bounds__(256) void edge_mfma(
    const float* __restrict__ coords, const float* __restrict__ h,
    const int* __restrict__ src, const int* __restrict__ dst,
    const float* __restrict__ efeat,
    const float* __restrict__ w1, const float* __restrict__ b1,
    const float* __restrict__ g, const float* __restrict__ bt,
    const float* __restrict__ w2, const float* __restrict__ b2,
    const float* __restrict__ cw1, const float* __restrict__ cb1,
    const float* __restrict__ cw2, const float* __restrict__ cb2,
    float* __restrict__ aggr, float* __restrict__ cnt, float* __restrict__ xacc)
{
    constexpr int IN = 143 + F;
    constexpr int KP = K1S * 32 + 8;
    __shared__ __align__(16) unsigned short xb[64 * KP];
    __shared__ __align__(16) float h1f[64 * 68];
    __shared__ __align__(16) unsigned short h1b[64 * 72];
    __shared__ float sums[256], sums2[256];
    __shared__ float stat_m[64], stat_r[64];
    __shared__ float coefp[4][64];
    __shared__ int dsts[64];
    __shared__ float xr_s[64][3], d2s[64];
    unsigned short* msgb = (unsigned short*)h1f;

    const int t  = threadIdx.x;
    const int wv = t >> 6;
    const int L  = t & 63;
    const int lm = L & 15;
    const int qd = L >> 4;
    const int e0 = blockIdx.x * 64;
    const int n  = wv * 16 + lm;

    bfrag8 w1f[K1S], w2f[2], c1f[2];
    #pragma unroll
    for (int kk = 0; kk < K1S; ++kk)
        #pragma unroll
        for (int j = 0; j < 8; ++j) {
            int k = kk * 32 + qd * 8 + j;
            w1f[kk][j] = (k < IN) ? bfbits(w1[k * 64 + n]) : (short)0;
        }
    #pragma unroll
    for (int kk = 0; kk < 2; ++kk)
        #pragma unroll
        for (int j = 0; j < 8; ++j) {
            int k = kk * 32 + qd * 8 + j;
            w2f[kk][j] = bfbits(w2[k * 64 + n]);
            c1f[kk][j] = bfbits(cw1[k * 64 + n]);
        }
    const float b1n = b1[n], b2n = b2[n], cb1n = cb1[n], cw2n = cw2[n];

    if (t < 64) {
        int e = e0 + t;
        int s = src[e], d = dst[e];
        dsts[t] = d;
        float x0 = coords[s * 3 + 0] - coords[d * 3 + 0];
        float x1 = coords[s * 3 + 1] - coords[d * 3 + 1];
        float x2 = coords[s * 3 + 2] - coords[d * 3 + 2];
        xr_s[t][0] = x0; xr_s[t][1] = x1; xr_s[t][2] = x2;
        d2s[t] = x0 * x0 + x1 * x1 + x2 * x2;
    }

    for (int p = 0; p < 16; ++p) {
        int e = (t >> 6) + 4 * p;
        int ge = e0 + e;
        int s = src[ge], d = dst[ge];
        int j = t & 63;
        xb[e * KP + j]      = bfbits(h[(size_t)s * 64 + j]);
        xb[e * KP + 64 + j] = bfbits(h[(size_t)d * 64 + j]);
    }
    for (int idx = t; idx < 64 * F; idx += 256) {
        int e = idx / F, f = idx - e * F;
        xb[e * KP + 128 + f] = bfbits(efeat[(size_t)(e0 + e) * F + f]);
    }
    {
        constexpr int PER = K1S * 32 - IN;
        for (int idx = t; idx < 64 * PER; idx += 256) {
            int e = idx / PER, k = idx - e * PER;
            xb[e * KP + IN + k] = 0;
        }
    }
    __syncthreads();
    for (int idx = t; idx < 64 * 15; idx += 256) {
        int e = idx / 15, s5 = idx - e * 15;
        xb[e * KP + 128 + F + s5] = bfbits(__expf(-d2s[e] * c_inv_sigma[s5]));
    }
    __syncthreads();

    #pragma unroll
    for (int m = 0; m < 4; ++m) {
        f32x4 acc = {0.f, 0.f, 0.f, 0.f};
        #pragma unroll
        for (int kk = 0; kk < K1S; ++kk) {
            bfrag8 a = *(const bfrag8*)&xb[(m * 16 + lm) * KP + kk * 32 + qd * 8];
            acc = __builtin_amdgcn_mfma_f32_16x16x32_bf16(a, w1f[kk], acc, 0, 0, 0);
        }
        #pragma unroll
        for (int r = 0; r < 4; ++r) {
            int mr = m * 16 + qd * 4 + r;
            float v = acc[r] + b1n;
            v = v > 0.f ? v : 0.01f * v;
            h1f[mr * 68 + n] = v;
        }
    }
    __syncthreads();

    {
        int e = t >> 2, seg = (t & 3) * 16;
        float s1 = 0.f, s2 = 0.f;
        #pragma unroll
        for (int j = 0; j < 16; ++j) {
            float v = h1f[e * 68 + seg + j];
            s1 += v; s2 += v * v;
        }
        sums[t] = s1; sums2[t] = s2;
    }
    __syncthreads();
    if (t < 64) {
        float s1 = sums[4 * t] + sums[4 * t + 1] + sums[4 * t + 2] + sums[4 * t + 3];
        float s2 = sums2[4 * t] + sums2[4 * t + 1] + sums2[4 * t + 2] + sums2[4 * t + 3];
        float mean = s1 * (1.f / 64.f);
        float var = s2 * (1.f / 64.f) - mean * mean;
        stat_m[t] = mean;
        stat_r[t] = rsqrtf(fmaxf(var, 0.f) + 1e-5f);
    }
    __syncthreads();
    for (int idx = t; idx < 4096; idx += 256) {
        int e = idx >> 6, j = idx & 63;
        float v = (h1f[e * 68 + j] - stat_m[e]) * stat_r[e] * g[j] + bt[j];
        h1b[e * 72 + j] = bfbits(v);
    }
    __syncthreads();

    #pragma unroll
    for (int m = 0; m < 4; ++m) {
        f32x4 acc = {0.f, 0.f, 0.f, 0.f};
        #pragma unroll
        for (int kk = 0; kk < 2; ++kk) {
            bfrag8 a = *(const bfrag8*)&h1b[(m * 16 + lm) * 72 + kk * 32 + qd * 8];
            acc = __builtin_amdgcn_mfma_f32_16x16x32_bf16(a, w2f[kk], acc, 0, 0, 0);
        }
        #pragma unroll
        for (int r = 0; r < 4; ++r) {
            int mr = m * 16 + qd * 4 + r;
            float v = acc[r] + b2n;
            atomicAdd(&aggr[(size_t)dsts[mr] * 64 + n], v);
            msgb[mr * 72 + n] = bfbits(v);
        }
    }
    __syncthreads();

    #pragma unroll
    for (int m = 0; m < 4; ++m) {
        f32x4 acc = {0.f, 0.f, 0.f, 0.f};
        #pragma unroll
        for (int kk = 0; kk < 2; ++kk) {
            bfrag8 a = *(const bfrag8*)&msgb[(m * 16 + lm) * 72 + kk * 32 + qd * 8];
            acc = __builtin_amdgcn_mfma_f32_16x16x32_bf16(a, c1f[kk], acc, 0, 0, 0);
        }
        #pragma unroll
        for (int r = 0; r < 4; ++r) {
            float v = acc[r] + cb1n;
            v = v > 0.f ? v : 0.01f * v;
            v *= cw2n;
            v += __shfl_xor(v, 1);
            v += __shfl_xor(v, 2);
            v += __shfl_xor(v, 4);
            v += __shfl_xor(v, 8);
            if (lm == 0) coefp[wv][m * 16 + qd * 4 + r] = v;
        }
    }
    __syncthreads();
    if (t < 64) {
        float coef = coefp[0][t] + coefp[1][t] + coefp[2][t] + coefp[3][t] + cb2[0];
        int d = dsts[t];
        atomicAdd(&cnt[d], 1.f);
        atomicAdd(&xacc[d * 3 + 0], xr_s[t][0] * coef);
        atomicAdd(&xacc[d * 3 + 1], xr_s[t][1] * coef);
        atomicAdd(&xacc[d * 3 + 2], xr_s[t][2] * coef);
    }
}

// ---------------- k/v projection (bf16 out) ----------------
__global__ __launch_bounds__(64) void linear64_kernel(
    const float* __restrict__ h, const float* __restrict__ w,
    bf16* __restrict__ out, int do_lrelu)
{
    int node = blockIdx.x;
    int j = threadIdx.x;
    __shared__ float x[64];
    x[j] = h[(size_t)node * 64 + j];
    __syncthreads();
    float acc = 0.f;
    #pragma unroll 8
    for (int i = 0; i < 64; ++i) acc += x[i] * w[i * 64 + j];
    if (do_lrelu) acc = acc > 0.f ? acc : 0.01f * acc;
    out[(size_t)node * 64 + j] = __float2bfloat16(acc);
}

// ---------------- u8 mask build ----------------
__global__ __launch_bounds__(256) void build_masks(
    const float* __restrict__ mask, unsigned char* __restrict__ m8,
    unsigned char* __restrict__ m8T, int R, int C)
{
    __shared__ __align__(16) unsigned char tl[64 * 80];
    int r0 = blockIdx.y * 64, c0 = blockIdx.x * 64;
    int t = threadIdx.x;
    int cs = (t & 15) * 4;
    #pragma unroll
    for (int rr = 0; rr < 4; ++rr) {
        int r = (t >> 4) + rr * 16;
        unsigned b0 = (mask[(size_t)(r0 + r) * C + c0 + cs + 0] != 0.f);
        unsigned b1 = (mask[(size_t)(r0 + r) * C + c0 + cs + 1] != 0.f);
        unsigned b2 = (mask[(size_t)(r0 + r) * C + c0 + cs + 2] != 0.f);
        unsigned b3 = (mask[(size_t)(r0 + r) * C + c0 + cs + 3] != 0.f);
        *(unsigned*)&m8[(size_t)(r0 + r) * C + c0 + cs] = b0 | (b1 << 8) | (b2 << 16) | (b3 << 24);
        tl[(cs + 0) * 80 + r] = (unsigned char)b0;
        tl[(cs + 1) * 80 + r] = (unsigned char)b1;
        tl[(cs + 2) * 80 + r] = (unsigned char)b2;
        tl[(cs + 3) * 80 + r] = (unsigned char)b3;
    }
    __syncthreads();
    {
        int c = t >> 2, rs = (t & 3) * 16;
        *(uint4*)&m8T[(size_t)(c0 + c) * R + r0 + rs] = *(const uint4*)&tl[c * 80 + rs];
    }
}

// ============ MFMA flash attention, both directions in one launch ============
// Per block: 64-row strip, wave wv owns rows [wv*16, wv*16+16) throughout.
// Online-softmax state (m, l, alpha) in registers. 3 barriers/tile.
template <int MMODE>  // 0: u8 mask, 1: strided f32 mask
__global__ __launch_bounds__(256) void attn_mfma(
    int nb1,
    const float* __restrict__ h1, const float* __restrict__ qw1,
    const bf16* __restrict__ k1, const bf16* __restrict__ v1,
    const unsigned char* __restrict__ m81, const float* __restrict__ mf1, long mrs1, long mcs1,
    float* __restrict__ pO1, float* __restrict__ pM1, float* __restrict__ pL1,
    int nrows1, int ncols1, int nsplit1,
    const float* __restrict__ h2, const float* __restrict__ qw2,
    const bf16* __restrict__ k2, const bf16* __restrict__ v2,
    const unsigned char* __restrict__ m82, const float* __restrict__ mf2, long mrs2, long mcs2,
    float* __restrict__ pO2, float* __restrict__ pM2, float* __restrict__ pL2,
    int nrows2, int ncols2, int nsplit2)
{
    const float *h, *qw, *mf;
    const bf16 *kkp, *vvp;
    const unsigned char* m8;
    long mrs, mcs;
    float *pO, *pM, *pL;
    int n_rows, n_cols, nsplit, bid;
    if ((int)blockIdx.x < nb1) {
        h = h1; qw = qw1; kkp = k1; vvp = v1; m8 = m81; mf = mf1; mrs = mrs1; mcs = mcs1;
        pO = pO1; pM = pM1; pL = pL1; n_rows = nrows1; n_cols = ncols1; nsplit = nsplit1;
        bid = blockIdx.x;
    } else {
        h = h2; qw = qw2; kkp = k2; vvp = v2; m8 = m82; mf = mf2; mrs = mrs2; mcs = mcs2;
        pO = pO2; pM = pM2; pL = pL2; n_rows = nrows2; n_cols = ncols2; nsplit = nsplit2;
        bid = blockIdx.x - nb1;
    }

    const int t  = threadIdx.x;
    const int wv = t >> 6;
    const int lm = t & 15;
    const int qd = (t & 63) >> 4;
    const int rb = bid / nsplit;
    const int sp = bid - rb * nsplit;
    const int r0 = rb * 64;
    const int cols_per = n_cols / nsplit;
    const int c_begin = sp * cols_per;

    __shared__ __align__(16) unsigned short qb[64 * 72];
    __shared__ __align__(16) unsigned short kvb[64 * 72];
    __shared__ __align__(16) unsigned short pb[64 * 72];
    __shared__ __align__(16) unsigned char mt[4096];

    // ---- stage h rows (bf16) into pb; qw^T into kvb ----
    {
        int r = t >> 3, seg = (t & 7) * 8;
        #pragma unroll
        for (int u = 0; u < 2; ++u) {
            int rr = r + 32 * u;
            const float* hp = h + (size_t)(r0 + rr) * 64 + seg;
            unsigned short tmp[8];
            #pragma unroll
            for (int j = 0; j < 8; ++j) tmp[j] = bfbits(hp[j]);
            *(uint4*)&qb[rr * 72 + seg] = *(uint4*)tmp;  // park h in qb temporarily
            const float* qp = qw + (size_t)rr * 64 + seg;
            #pragma unroll
            for (int j = 0; j < 8; ++j) kvb[(seg + j) * 72 + rr] = bfbits(qp[j]);
        }
    }
    __syncthreads();
    // Q = lrelu(h @ qw) -> pb (C-layout scatter), then copy to qb after sync
    {
        bfrag8 a0 = *(const bfrag8*)&qb[(wv * 16 + lm) * 72 + qd * 8];
        bfrag8 a1 = *(const bfrag8*)&qb[(wv * 16 + lm) * 72 + 32 + qd * 8];
        #pragma unroll
        for (int ns = 0; ns < 4; ++ns) {
            f32x4 acc = {0.f, 0.f, 0.f, 0.f};
            bfrag8 b0 = *(const bfrag8*)&kvb[(ns * 16 + lm) * 72 + qd * 8];
            bfrag8 b1 = *(const bfrag8*)&kvb[(ns * 16 + lm) * 72 + 32 + qd * 8];
            acc = __builtin_amdgcn_mfma_f32_16x16x32_bf16(a0, b0, acc, 0, 0, 0);
            acc = __builtin_amdgcn_mfma_f32_16x16x32_bf16(a1, b1, acc, 0, 0, 0);
            #pragma unroll
            for (int r = 0; r < 4; ++r) {
                float v = acc[r];
                v = v > 0.f ? v : 0.01f * v;
                pb[(wv * 16 + qd * 4 + r) * 72 + ns * 16 + lm] = bfbits(v);
            }
        }
    }
    __syncthreads();
    // move Q into qb (qb's h copy is dead)
    for (int idx = t; idx < 64 * 9; idx += 256) {
        int r = idx / 9, seg = (idx - r * 9) * 8;
        if (seg < 64) *(uint4*)&qb[r * 72 + seg] = *(const uint4*)&pb[r * 72 + seg];
    }
    __syncthreads();

    float rm[4], rl[4];
    #pragma unroll
    for (int r = 0; r < 4; ++r) { rm[r] = -1e30f; rl[r] = 0.f; }
    f32x4 o[4];
    #pragma unroll
    for (int ds = 0; ds < 4; ++ds) o[ds] = (f32x4){0.f, 0.f, 0.f, 0.f};

    for (int c0 = c_begin; c0 < c_begin + cols_per; c0 += 64) {
        // ---- stage K (natural rows, bf16 16B copies) + mask ----
        {
            int c = t >> 3, seg = (t & 7) * 8;
            #pragma unroll
            for (int u = 0; u < 2; ++u) {
                int cc = c + 32 * u;
                *(uint4*)&kvb[cc * 72 + seg] =
                    *(const uint4*)(kkp + (size_t)(c0 + cc) * 64 + seg);
            }
        }
        if (MMODE == 0) {
            int r = t >> 2, seg = (t & 3) * 16;
            *(uint4*)&mt[r * 64 + seg] =
                *(const uint4*)&m8[(size_t)(r0 + r) * n_cols + c0 + seg];
        } else {
            #pragma unroll
            for (int u = 0; u < 16; ++u) {
                int i = t + 256 * u;
                int r = i >> 6, c = i & 63;
                mt[r * 64 + c] = (unsigned char)(
                    mf[(size_t)(r0 + r) * mrs + (size_t)(c0 + c) * mcs] != 0.f);
            }
        }
        __syncthreads();

        // ---- S = Q K^T (MFMA), masked, online softmax in registers ----
        f32x4 s[4];
        {
            bfrag8 a0 = *(const bfrag8*)&qb[(wv * 16 + lm) * 72 + qd * 8];
            bfrag8 a1 = *(const bfrag8*)&qb[(wv * 16 + lm) * 72 + 32 + qd * 8];
            #pragma unroll
            for (int ns = 0; ns < 4; ++ns) {
                f32x4 acc = {0.f, 0.f, 0.f, 0.f};
                bfrag8 b0 = *(const bfrag8*)&kvb[(ns * 16 + lm) * 72 + qd * 8];
                bfrag8 b1 = *(const bfrag8*)&kvb[(ns * 16 + lm) * 72 + 32 + qd * 8];
                acc = __builtin_amdgcn_mfma_f32_16x16x32_bf16(a0, b0, acc, 0, 0, 0);
                acc = __builtin_amdgcn_mfma_f32_16x16x32_bf16(a1, b1, acc, 0, 0, 0);
                s[ns] = acc;
            }
        }
        float alpha[4];
        #pragma unroll
        for (int r = 0; r < 4; ++r) {
            int rloc = wv * 16 + qd * 4 + r;
            float v0 = mt[rloc * 64 +  0 + lm] ? s[0][r] : -1000.f;
            float v1 = mt[rloc * 64 + 16 + lm] ? s[1][r] : -1000.f;
            float v2 = mt[rloc * 64 + 32 + lm] ? s[2][r] : -1000.f;
            float v3 = mt[rloc * 64 + 48 + lm] ? s[3][r] : -1000.f;
            float mx = quad_max(fmaxf(fmaxf(v0, v1), fmaxf(v2, v3)));
            float mn = fmaxf(rm[r], mx);
            float al = __expf(rm[r] - mn);
            rm[r] = mn; alpha[r] = al;
            float p0 = __expf(v0 - mn), p1 = __expf(v1 - mn);
            float p2 = __expf(v2 - mn), p3 = __expf(v3 - mn);
            pb[rloc * 72 +  0 + lm] = bfbits(p0);
            pb[rloc * 72 + 16 + lm] = bfbits(p1);
            pb[rloc * 72 + 32 + lm] = bfbits(p2);
            pb[rloc * 72 + 48 + lm] = bfbits(p3);
            float ls = quad_sum(p0 + p1 + p2 + p3);
            rl[r] = rl[r] * al + ls;
        }
        #pragma unroll
        for (int ds = 0; ds < 4; ++ds)
            #pragma unroll
            for (int r = 0; r < 4; ++r) o[ds][r] *= alpha[r];
        __syncthreads();  // all K-reads complete

        // ---- stage V^T into kvb ----
        {
            int c = t >> 3, seg = (t & 7) * 8;
            #pragma unroll
            for (int u = 0; u < 2; ++u) {
                int cc = c + 32 * u;
                uint4 raw = *(const uint4*)(vvp + (size_t)(c0 + cc) * 64 + seg);
                unsigned short* pr = (unsigned short*)&raw;
                #pragma unroll
                for (int j = 0; j < 8; ++j) kvb[(seg + j) * 72 + cc] = pr[j];
            }
        }
        __syncthreads();

        // ---- O += P @ V ----
        {
            bfrag8 a0 = *(const bfrag8*)&pb[(wv * 16 + lm) * 72 + qd * 8];
            bfrag8 a1 = *(const bfrag8*)&pb[(wv * 16 + lm) * 72 + 32 + qd * 8];
            #pragma unroll
            for (int ds = 0; ds < 4; ++ds) {
                bfrag8 b0 = *(const bfrag8*)&kvb[(ds * 16 + lm) * 72 + qd * 8];
                bfrag8 b1 = *(const bfrag8*)&kvb[(ds * 16 + lm) * 72 + 32 + qd * 8];
                o[ds] = __builtin_amdgcn_mfma_f32_16x16x32_bf16(a0, b0, o[ds], 0, 0, 0);
                o[ds] = __builtin_amdgcn_mfma_f32_16x16x32_bf16(a1, b1, o[ds], 0, 0, 0);
            }
        }
        __syncthreads();  // V-reads done before next K staging
    }

    // ---- write split partials ----
    #pragma unroll
    for (int ds = 0; ds < 4; ++ds)
        #pragma unroll
        for (int r = 0; r < 4; ++r) {
            int row = r0 + wv * 16 + qd * 4 + r;
            pO[((size_t)sp * n_rows + row) * 64 + ds * 16 + lm] = o[ds][r];
        }
    if (lm == 0) {
        #pragma unroll
        for (int r = 0; r < 4; ++r) {
            int row = r0 + wv * 16 + qd * 4 + r;
            pM[(size_t)sp * n_rows + row] = rm[r];
            pL[(size_t)sp * n_rows + row] = rl[r];
        }
    }
}

// ---------------- merge split partials ----------------
__global__ __launch_bounds__(64) void attn_merge(
    const float* __restrict__ pO, const float* __restrict__ pM, const float* __restrict__ pL,
    float* __restrict__ out, int n_rows, int nsplit)
{
    int r = blockIdx.x;
    int d = threadIdx.x;
    float mstar = -1e30f;
    for (int s = 0; s < nsplit; ++s) mstar = fmaxf(mstar, pM[(size_t)s * n_rows + r]);
    float L = 0.f, O = 0.f;
    for (int s = 0; s < nsplit; ++s) {
        float w = __expf(pM[(size_t)s * n_rows + r] - mstar);
        L += pL[(size_t)s * n_rows + r] * w;
        O += pO[((size_t)s * n_rows + r) * 64 + d] * w;
    }
    out[(size_t)r * 64 + d] = O / L;
}

// ---------------- per-row attention (tier-2 fallback) ----------------
__global__ __launch_bounds__(256) void attn_row_kernel(
    const float* __restrict__ h, const float* __restrict__ qw,
    const bf16* __restrict__ k, const bf16* __restrict__ v,
    const float* __restrict__ mask, long mrs, long mcs,
    float* __restrict__ out, int n_cols)
{
    int row = blockIdx.x;
    int tid = threadIdx.x;
    extern __shared__ float sc[];
    __shared__ float hrow[64];
    __shared__ float qrow[64];
    __shared__ float red[4];
    __shared__ float opart[4][64];

    if (tid < 64) hrow[tid] = h[(size_t)row * 64 + tid];
    __syncthreads();
    if (tid < 64) {
        float a = 0.f;
        #pragma unroll 8
        for (int i = 0; i < 64; ++i) a += hrow[i] * qw[i * 64 + tid];
        qrow[tid] = a > 0.f ? a : 0.01f * a;
    }
    __syncthreads();

    float lmax = -1e30f;
    for (int c = tid; c < n_cols; c += 256) {
        const bf16* kr = k + (size_t)c * 64;
        float s = 0.f;
        #pragma unroll 8
        for (int i = 0; i < 64; ++i) s += qrow[i] * ldkv(kr, i);
        float m = mask[(size_t)row * mrs + (size_t)c * mcs];
        s = m * s - 1000.f * (1.f - m);
        sc[c] = s;
        lmax = fmaxf(lmax, s);
    }
    #pragma unroll
    for (int o = 32; o > 0; o >>= 1) lmax = fmaxf(lmax, __shfl_xor(lmax, o, 64));
    int wid = tid >> 6;
    if ((tid & 63) == 0) red[wid] = lmax;
    __syncthreads();
    float bmax = fmaxf(fmaxf(red[0], red[1]), fmaxf(red[2], red[3]));
    __syncthreads();

    float lsum = 0.f;
    for (int c = tid; c < n_cols; c += 256) {
        float e = __expf(sc[c] - bmax);
        sc[c] = e;
        lsum += e;
    }
    lsum = wave_sum(lsum);
    if ((tid & 63) == 0) red[wid] = lsum;
    __syncthreads();
    float inv = 1.f / (red[0] + red[1] + red[2] + red[3]);

    int dd = tid & 63;
    float o = 0.f;
    for (int c = wid; c < n_cols; c += 4) o += sc[c] * ldkv(v, (size_t)c * 64 + dd);
    opart[wid][dd] = o;
    __syncthreads();
    if (wid == 0)
        out[(size_t)row * 64 + dd] =
            (opart[0][dd] + opart[1][dd] + opart[2][dd] + opart[3][dd]) * inv;
}

// ---------------- node feature update ----------------
__global__ __launch_bounds__(64) void node_kernel(
    const float* __restrict__ h, const float* __restrict__ aggr,
    const float* __restrict__ cnt, const float* att,  // aliases h_out
    const float* __restrict__ orig_h,
    const float* __restrict__ w1, const float* __restrict__ b1,
    const float* __restrict__ g, const float* __restrict__ bt,
    const float* __restrict__ w2, const float* __restrict__ b2,
    float* h_out)
{
    int node = blockIdx.x;
    int j = threadIdx.x;
    __shared__ float xin[256];
    __shared__ float hbuf[64];
    float invc = 1.f / fmaxf(cnt[node], 1.f);
    float hv = h[(size_t)node * 64 + j];
    xin[j]       = hv;
    xin[64 + j]  = aggr[(size_t)node * 64 + j] * invc;
    xin[128 + j] = att[(size_t)node * 64 + j];
    xin[192 + j] = orig_h[(size_t)node * 64 + j];
    __syncthreads();
    float acc = b1[j];
    #pragma unroll 4
    for (int i = 0; i < 256; ++i) acc += xin[i] * w1[i * 64 + j];
    acc = acc > 0.f ? acc : 0.01f * acc;
    float mean = wave_sum(acc) * (1.f / 64.f);
    float cv = acc - mean;
    float var = wave_sum(cv * cv) * (1.f / 64.f);
    float y = cv * rsqrtf(var + 1e-5f) * g[j] + bt[j];
    hbuf[j] = y;
    __syncthreads();
    float o = b2[j];
    #pragma unroll 8
    for (int i = 0; i < 64; ++i) o += hbuf[i] * w2[i * 64 + j];
    h_out[(size_t)node * 64 + j] = 0.5f * o + 0.5f * hv;
}

// ---------------- coordinate output ----------------
__global__ void coord_kernel(
    const float* __restrict__ orig, const float* __restrict__ coords,
    const float* __restrict__ xacc, const float* __restrict__ cnt,
    float* __restrict__ out, int n3)
{
    int i = blockIdx.x * blockDim.x + threadIdx.x;
    if (i >= n3) return;
    int node = i / 3;
    float invc = 1.f / fmaxf(cnt[node], 1.f);
    out[i] = 0.25f * orig[i] + 0.75f * coords[i] + xacc[i] * invc;
}

extern "C" void kernel_launch(void* const* d_in, const int* in_sizes, int n_in,
                              void* d_out, int out_size, void* d_ws, size_t ws_size,
                              hipStream_t stream)
{
    const float* coords_lig      = (const float*)d_in[0];
    const float* h_lig           = (const float*)d_in[1];
    const float* orig_h_lig      = (const float*)d_in[2];
    const float* orig_coords_lig = (const float*)d_in[3];
    const float* coords_rec      = (const float*)d_in[4];
    const float* h_rec           = (const float*)d_in[5];
    const float* orig_h_rec      = (const float*)d_in[6];
    const float* orig_coords_rec = (const float*)d_in[7];
    const int* lig_src   = (const int*)d_in[8];
    const int* lig_dst   = (const int*)d_in[9];
    const float* lig_efeat = (const float*)d_in[10];
    const int* rec_src   = (const int*)d_in[11];
    const int* rec_dst   = (const int*)d_in[12];
    const float* rec_efeat = (const float*)d_in[13];
    const float* mask      = (const float*)d_in[14];
    const float *lig_em_w1 = (const float*)d_in[15], *lig_em_b1 = (const float*)d_in[16];
    const float *lig_em_g  = (const float*)d_in[17], *lig_em_bt = (const float*)d_in[18];
    const float *lig_em_w2 = (const float*)d_in[19], *lig_em_b2 = (const float*)d_in[20];
    const float *rec_em_w1 = (const float*)d_in[21], *rec_em_b1 = (const float*)d_in[22];
    const float *rec_em_g  = (const float*)d_in[23], *rec_em_bt = (const float*)d_in[24];
    const float *rec_em_w2 = (const float*)d_in[25], *rec_em_b2 = (const float*)d_in[26];
    const float *lig_cm_w1 = (const float*)d_in[27], *lig_cm_b1 = (const float*)d_in[28];
    const float *lig_cm_w2 = (const float*)d_in[29], *lig_cm_b2 = (const float*)d_in[30];
    const float *rec_cm_w1 = (const float*)d_in[31], *rec_cm_b1 = (const float*)d_in[32];
    const float *rec_cm_w2 = (const float*)d_in[33], *rec_cm_b2 = (const float*)d_in[34];
    const float *q_lig_w = (const float*)d_in[35], *k_lig_w = (const float*)d_in[36];
    const float *v_lig_w = (const float*)d_in[37], *q_rec_w = (const float*)d_in[38];
    const float *k_rec_w = (const float*)d_in[39], *v_rec_w = (const float*)d_in[40];
    const float *lig_nm_w1 = (const float*)d_in[41], *lig_nm_b1 = (const float*)d_in[42];
    const float *lig_nm_g  = (const float*)d_in[43], *lig_nm_bt = (const float*)d_in[44];
    const float *lig_nm_w2 = (const float*)d_in[45], *lig_nm_b2 = (const float*)d_in[46];
    const float *rec_nm_w1 = (const float*)d_in[47], *rec_nm_b1 = (const float*)d_in[48];
    const float *rec_nm_g  = (const float*)d_in[49], *rec_nm_bt = (const float*)d_in[50];
    const float *rec_nm_w2 = (const float*)d_in[51], *rec_nm_b2 = (const float*)d_in[52];

    char* wsb = (char*)d_ws;
    float* aggr_l = (float*)(wsb + 16);
    float* aggr_r = aggr_l + (size_t)N_LIG * 64;
    float* cnt_l  = aggr_r + (size_t)N_REC * 64;
    float* cnt_r  = cnt_l + N_LIG;
    float* xacc_l = cnt_r + N_REC;
    float* xacc_r = xacc_l + (size_t)N_LIG * 3;
    const size_t zero_floats =
        (size_t)N_LIG * 64 + (size_t)N_REC * 64 + N_LIG + N_REC + N_LIG * 3 + N_REC * 3;
    const size_t core_b = 16 + zero_floats * 4;
    const size_t kv_b = (size_t)(N_LIG + N_REC) * 64 * 2 * 2;   // bf16 k+v both graphs
    const size_t part_b = ((size_t)4 * N_LIG * 64 + (size_t)2 * N_REC * 64) * 4
                        + ((size_t)4 * N_LIG + (size_t)2 * N_REC) * 2 * 4;
    const size_t m8_b = (size_t)N_LIG * N_REC;

    int tier;
    if (ws_size >= core_b + kv_b + part_b + 2 * m8_b) tier = 0;
    else if (ws_size >= core_b + kv_b + part_b) tier = 1;
    else tier = 2;

    char* kv_base = wsb + core_b;
    bf16* kb_l = (bf16*)kv_base;
    bf16* vb_l = kb_l + (size_t)N_LIG * 64;
    bf16* kb_r = vb_l + (size_t)N_LIG * 64;
    bf16* vb_r = kb_r + (size_t)N_REC * 64;
    float* pO1 = (float*)(kv_base + kv_b);
    float* pO2 = pO1 + (size_t)4 * N_LIG * 64;
    float* pM1 = pO2 + (size_t)2 * N_REC * 64;
    float* pL1 = pM1 + (size_t)4 * N_LIG;
    float* pM2 = pL1 + (size_t)4 * N_LIG;
    float* pL2 = pM2 + (size_t)2 * N_REC;
    unsigned char* m8  = (unsigned char*)(kv_base + kv_b + part_b);
    unsigned char* m8T = m8 + m8_b;

    float* out = (float*)d_out;
    float* x_lig_o = out;
    float* h_lig_o = out + 12288;
    float* x_rec_o = out + 274432;
    float* h_rec_o = out + 299008;

    zero_kernel<<<((int)zero_floats + 255) / 256, 256, 0, stream>>>(aggr_l, (int)zero_floats);

    // k/v projections (bf16)
    linear64_kernel<<<N_LIG, 64, 0, stream>>>(h_lig, k_lig_w, kb_l, 1);
    linear64_kernel<<<N_LIG, 64, 0, stream>>>(h_lig, v_lig_w, vb_l, 0);
    linear64_kernel<<<N_REC, 64, 0, stream>>>(h_rec, k_rec_w, kb_r, 1);
    linear64_kernel<<<N_REC, 64, 0, stream>>>(h_rec, v_rec_w, vb_r, 0);

    // MFMA edge kernels
    edge_mfma<F_LIGc, 5><<<E_LIG / 64, 256, 0, stream>>>(
        coords_lig, h_lig, lig_src, lig_dst, lig_efeat,
        lig_em_w1, lig_em_b1, lig_em_g, lig_em_bt, lig_em_w2, lig_em_b2,
        lig_cm_w1, lig_cm_b1, lig_cm_w2, lig_cm_b2,
        aggr_l, cnt_l, xacc_l);
    edge_mfma<F_RECc, 6><<<E_REC / 64, 256, 0, stream>>>(
        coords_rec, h_rec, rec_src, rec_dst, rec_efeat,
        rec_em_w1, rec_em_b1, rec_em_g, rec_em_bt, rec_em_w2, rec_em_b2,
        rec_cm_w1, rec_cm_b1, rec_cm_w2, rec_cm_b2,
        aggr_r, cnt_r, xacc_r);

    // attention (both directions in one launch)
    const int nb1 = (N_LIG / 64) * 4;
    const int nb2 = (N_REC / 64) * 2;
    if (tier <= 1) {
        if (tier == 0) {
            dim3 bg(N_REC / 64, N_LIG / 64);
            build_masks<<<bg, 256, 0, stream>>>(mask, m8, m8T, N_LIG, N_REC);
            attn_mfma<0><<<nb1 + nb2, 256, 0, stream>>>(
                nb1,
                h_lig, q_lig_w, kb_r, vb_r, m8, mask, 0L, 0L,
                pO1, pM1, pL1, N_LIG, N_REC, 4,
                h_rec, q_rec_w, kb_l, vb_l, m8T, mask, 0L, 0L,
                pO2, pM2, pL2, N_REC, N_LIG, 2);
        } else {
            attn_mfma<1><<<nb1 + nb2, 256, 0, stream>>>(
                nb1,
                h_lig, q_lig_w, kb_r, vb_r, (const unsigned char*)0, mask, (long)N_REC, 1L,
                pO1, pM1, pL1, N_LIG, N_REC, 4,
                h_rec, q_rec_w, kb_l, vb_l, (const unsigned char*)0, mask, 1L, (long)N_REC,
                pO2, pM2, pL2, N_REC, N_LIG, 2);
        }
        attn_merge<<<N_LIG, 64, 0, stream>>>(pO1, pM1, pL1, h_lig_o, N_LIG, 4);
        attn_merge<<<N_REC, 64, 0, stream>>>(pO2, pM2, pL2, h_rec_o, N_REC, 2);
    } else {
        attn_row_kernel<<<N_LIG, 256, N_REC * sizeof(float), stream>>>(
            h_lig, q_lig_w, kb_r, vb_r, mask, (long)N_REC, 1L, h_lig_o, N_REC);
        attn_row_kernel<<<N_REC, 256, N_LIG * sizeof(float), stream>>>(
            h_rec, q_rec_w, kb_l, vb_l, mask, 1L, (long)N_REC, h_rec_o, N_LIG);
    }

    // node updates
    node_kernel<<<N_LIG, 64, 0, stream>>>(
        h_lig, aggr_l, cnt_l, h_lig_o, orig_h_lig,
        lig_nm_w1, lig_nm_b1, lig_nm_g, lig_nm_bt, lig_nm_w2, lig_nm_b2, h_lig_o);
    node_kernel<<<N_REC, 64, 0, stream>>>(
        h_rec, aggr_r, cnt_r, h_rec_o, orig_h_rec,
        rec_nm_w1, rec_nm_b1, rec_nm_g, rec_nm_bt, rec_nm_w2, rec_nm_b2, h_rec_o);

    // coordinate outputs
    coord_kernel<<<(N_LIG * 3 + 255) / 256, 256, 0, stream>>>(
        orig_coords_lig, coords_lig, xacc_l, cnt_l, x_lig_o, N_LIG * 3);
    coord_kernel<<<(N_REC * 3 + 255) / 256, 256, 0, stream>>>(
        orig_coords_rec, coords_rec, xacc_r, cnt_r, x_rec_o, N_REC * 3);
}